// Round 5
// baseline (855.925 us; speedup 1.0000x reference)
//
#include <hip/hip_runtime.h>
#include <hip/hip_fp16.h>

#define VOX (128 * 128 * 128)   // 2097152
#define P 130                   // padded dim
#define PP (P * P)              // 16900
#define PVOX (P * P * P)        // 2197000
#define LROW 130
#define PLANE (6 * LROW)        // 780 16B-units per staged dz-plane

typedef unsigned short u16;
typedef _Float16 f16x2 __attribute__((ext_vector_type(2)));
typedef _Float16 f16x8 __attribute__((ext_vector_type(8)));
typedef __attribute__((ext_vector_type(4))) float f32x4;

__device__ __forceinline__ u16 f2h(float f) {
    return __builtin_bit_cast(unsigned short, (_Float16)f);
}
__device__ __forceinline__ unsigned pkh_relu(float a, float b) {
    float ra = a > 0.f ? a : 0.f, rb = b > 0.f ? b : 0.f;
    return (unsigned)f2h(ra) | ((unsigned)f2h(rb) << 16);
}
__device__ __forceinline__ f16x2 h2(unsigned u) { return __builtin_bit_cast(f16x2, u); }

// dot2: acc += a.x*b.x + a.y*b.y  (f32 accumulate, single V_DOT2_F32_F16)
__device__ __forceinline__ float dot2(unsigned a, unsigned b, float c) {
#if __has_builtin(__builtin_amdgcn_fdot2)
    return __builtin_amdgcn_fdot2(h2(a), h2(b), c, false);
#else
    f16x2 av = h2(a), bv = h2(b);
    c = fmaf((float)av.x, (float)bv.x, c);
    return fmaf((float)av.y, (float)bv.y, c);
#endif
}

// fast tanh: 1 - 2/(1+e^{2x})
__device__ __forceinline__ float fast_tanh(float x) {
    float e = __expf(2.0f * x);
    return 1.0f - 2.0f * __builtin_amdgcn_rcpf(1.0f + e);
}

// async global->LDS DMA, 16B per lane. LDS dest = wave-uniform base + lane*16.
__device__ __forceinline__ void gload_lds16(const u16* g, u16* l) {
    __builtin_amdgcn_global_load_lds(
        (const __attribute__((address_space(1))) unsigned int*)g,
        (__attribute__((address_space(3))) unsigned int*)l,
        16, 0, 0);
}

// heavy integrate (batch 0 only): x0 full (incl halo), weight prep, halo zeroing.
//  x0 padded f16 [130^3] = cube * (1 + 0.1*sin(2pi*(d+h+w)/384)), halo = 0
//  zero halo shells of x1 (8ch) / x2 (16ch)
//  w2frag[(s*64+lane)*8+j] = f16(w2[oc=lane&15][ic=j][tap=s*4+(lane>>4)]), 0 if tap>26
//  w3p[tap*8+j] = packed f16 pair (w3[2j][tap], w3[2j+1][tap])
//  w1c[tap*8+c] = f32 w1[c][tap]   (channel-contiguous for conv1 scalar FMA)
__global__ __launch_bounds__(256) void integrate_kernel(
    const float* __restrict__ in, u16* __restrict__ x0,
    const float* __restrict__ w1, const float* __restrict__ w2,
    const float* __restrict__ w3, u16* __restrict__ w2frag,
    unsigned* __restrict__ w3p, float* __restrict__ w1c,
    u16* __restrict__ x1, u16* __restrict__ x2) {
    int i = blockIdx.x * 256 + threadIdx.x;
    if (i < 3584) {
        int j = i & 7, l = (i >> 3) & 63, s = i >> 9;
        int tap = s * 4 + (l >> 4), oc = l & 15;
        float v = (tap < 27) ? w2[(oc * 8 + j) * 27 + tap] : 0.0f;
        w2frag[i] = f2h(v);
    }
    if (i < 216) {
        int tap = i >> 3, j = i & 7;
        w3p[i] = (unsigned)f2h(w3[(2 * j) * 27 + tap]) |
                 ((unsigned)f2h(w3[(2 * j + 1) * 27 + tap]) << 16);
        // w1c: tap-major, 8 channels contiguous
        int c = i & 7;
        w1c[i] = w1[c * 27 + tap];
    }
    if (i >= PVOX) return;
    int d = i / PP;
    int r = i - d * PP;
    int h = r / P;
    int w = r - h * P;
    const bool interior = (d >= 1 && d <= 128 && h >= 1 && h <= 128 && w >= 1 && w <= 128);
    float v = 0.0f;
    if (interior) {
        int s = (d - 1) + (h - 1) + (w - 1);
        float fld = 1.0f + 0.1f * __sinf(6.283185307179586f * (float)s / 384.0f);
        v = in[(size_t)(d - 1) * 16384 + (h - 1) * 128 + (w - 1)] * fld;
    } else {
        uint4 z = {0u, 0u, 0u, 0u};
        *(uint4*)(x1 + (size_t)i * 8) = z;
        *(uint4*)(x2 + (size_t)i * 16) = z;
        *(uint4*)(x2 + (size_t)i * 16 + 8) = z;
    }
    x0[i] = f2h(v);
}

// light integrate (batch 1): x0 interior only (halo already zero; prep idempotent)
__global__ __launch_bounds__(256) void integrate_light_kernel(
    const float* __restrict__ in, u16* __restrict__ x0) {
    const int i = blockIdx.x * 256 + threadIdx.x;  // VOX threads exactly
    const int d = i >> 14, h = (i >> 7) & 127, w = i & 127;
    const int s = d + h + w;
    const float fld = 1.0f + 0.1f * __sinf((float)s * 0.016362461737446838f);
    x0[(size_t)(d + 1) * PP + (h + 1) * P + (w + 1)] = f2h(in[i] * fld);
}

// conv1: x0 padded f16 [130^3] -> x1 f16 channels-last padded [130^3][8], relu.
// Strip 4(h) x 2(w) voxels/thread. SCALAR-FMA form: acc as 64 flat floats,
// weights via wave-uniform constant-offset loads (SGPR-resident s_load),
// acts as 4 scalar floats -> each FMA is one v_fmac_f32 (sgpr, vgpr), no
// operand-vector rebuild movs. 1728 fma/thread is the floor.
__global__ __launch_bounds__(256) void conv1_kernel(
    const u16* __restrict__ x0, const float* __restrict__ w1c,
    const float* __restrict__ b1, u16* __restrict__ x1) {
    const int t = blockIdx.x * 256 + threadIdx.x;  // VOX/8 threads
    const int w0 = (t & 63) * 2;
    const int h0 = ((t >> 6) & 31) * 4;
    const int d = t >> 11;

    float acc[4][2][8];  // [i(h)][m(w)][c]
#pragma unroll
    for (int c = 0; c < 8; ++c) {
        const float b = b1[c];
#pragma unroll
        for (int i = 0; i < 4; ++i) { acc[i][0][c] = b; acc[i][1][c] = b; }
    }

#pragma unroll
    for (int dz = 0; dz < 3; ++dz) {
        const u16* zb = x0 + (size_t)(d + dz) * PP + (size_t)h0 * P + w0;
        const float* wz = w1c + dz * 9 * 8;  // 72 floats, uniform const offsets
#pragma unroll
        for (int r = 0; r < 6; ++r) {
            const u16* rp = zb + r * P;
            const unsigned u0 = *(const unsigned*)rp;
            const unsigned u1 = *(const unsigned*)(rp + 2);
            float vv[4];
            vv[0] = (float)h2(u0).x; vv[1] = (float)h2(u0).y;
            vv[2] = (float)h2(u1).x; vv[3] = (float)h2(u1).y;
#pragma unroll
            for (int dy = 0; dy < 3; ++dy) {
                const int i = r - dy;
                if (i < 0 || i > 3) continue;  // resolved at compile time
#pragma unroll
                for (int dx = 0; dx < 3; ++dx) {
                    const float a0 = vv[dx];
                    const float a1 = vv[dx + 1];
                    const float* wp = wz + (dy * 3 + dx) * 8;
#pragma unroll
                    for (int c = 0; c < 8; ++c) {
                        const float wt = wp[c];
                        acc[i][0][c] = fmaf(wt, a0, acc[i][0][c]);
                        acc[i][1][c] = fmaf(wt, a1, acc[i][1][c]);
                    }
                }
            }
        }
    }
    const size_t e0 = ((size_t)(d + 1) * P + (h0 + 1)) * P + (w0 + 1);
#pragma unroll
    for (int i = 0; i < 4; ++i) {
        uint4 oA, oB;
        oA.x = pkh_relu(acc[i][0][0], acc[i][0][1]);
        oA.y = pkh_relu(acc[i][0][2], acc[i][0][3]);
        oA.z = pkh_relu(acc[i][0][4], acc[i][0][5]);
        oA.w = pkh_relu(acc[i][0][6], acc[i][0][7]);
        oB.x = pkh_relu(acc[i][1][0], acc[i][1][1]);
        oB.y = pkh_relu(acc[i][1][2], acc[i][1][3]);
        oB.z = pkh_relu(acc[i][1][4], acc[i][1][5]);
        oB.w = pkh_relu(acc[i][1][6], acc[i][1][7]);
        *(uint4*)(x1 + (e0 + (size_t)i * P) * 8) = oA;
        *(uint4*)(x1 + (e0 + (size_t)i * P + 1) * 8) = oB;
    }
}

// conv2: rolling-d LDS-staged implicit-GEMM MFMA, async DMA staging.
// d-chunk = 8 -> grid 512 blocks = 2/CU, ALL resident (cap 3/CU at 49.9KB):
// zero occupancy-quantization tail. One barrier per d-step.
__global__ __launch_bounds__(256) void conv2_mfma_kernel(
    const u16* __restrict__ x1, const u16* __restrict__ w2frag,
    const float* __restrict__ b2, u16* __restrict__ x2) {
    __shared__ u16 sm[4 * PLANE * 8];  // 49920 B

    const int tid = threadIdx.x;
    const int lane = tid & 63;
    const int wv = tid >> 6;  // output h-row offset 0..3
    const int q = lane >> 4;
    const int mi = lane & 15;
    const int D0 = (blockIdx.x >> 5) * 8;   // d-chunk base (unpadded out d)
    const int h0 = (blockIdx.x & 31) * 4;   // h-tile base

    // weight A-frags (7KB table, L1-resident)
    f16x8 wf[7];
#pragma unroll
    for (int s = 0; s < 7; ++s)
        wf[s] = *(const f16x8*)(w2frag + (size_t)(s * 64 + lane) * 8);

    // async stage planes D0..D0+2 (padded plane index pd covers rows h0..h0+5)
#pragma unroll
    for (int p = 0; p < 3; ++p) {
        const int pd = D0 + p;
        const int slot = pd & 3;
        const u16* gb = x1 + ((size_t)(pd * P + h0) * P) * 8;
        u16* lb = sm + (size_t)slot * PLANE * 8;
#pragma unroll
        for (int k = 0; k < 3; ++k) {
            const int u0 = wv * 64 + k * 256;
            gload_lds16(gb + (size_t)(u0 + lane) * 8, lb + (size_t)u0 * 8);
        }
        if (wv == 0 && lane < PLANE - 768)
            gload_lds16(gb + (size_t)(768 + lane) * 8, lb + (size_t)768 * 8);
    }
    __syncthreads();

    const float4 bv = *(const float4*)(b2 + q * 4);

#pragma unroll 1
    for (int i = 0; i < 8; ++i) {
        const int dout = D0 + i;

        // async prefetch plane dout+3 into its ring slot (unread this step)
        if (i < 7) {
            const int pd = dout + 3;
            const int slot = pd & 3;
            const u16* gb = x1 + ((size_t)(pd * P + h0) * P) * 8;
            u16* lb = sm + (size_t)slot * PLANE * 8;
#pragma unroll
            for (int k = 0; k < 3; ++k) {
                const int u0 = wv * 64 + k * 256;
                gload_lds16(gb + (size_t)(u0 + lane) * 8, lb + (size_t)u0 * 8);
            }
            if (wv == 0 && lane < PLANE - 768)
                gload_lds16(gb + (size_t)(768 + lane) * 8, lb + (size_t)768 * 8);
        }

        // compute output plane dout from slots (dout..dout+2)&3
        f32x4 acc[8];
#pragma unroll
        for (int t = 0; t < 8; ++t) acc[t] = (f32x4){0.f, 0.f, 0.f, 0.f};

#pragma unroll
        for (int s = 0; s < 7; ++s) {
            int tap = s * 4 + q;
            if (tap > 26) tap = 26;  // pad tap: weight frag is zero there
            const int dz = tap / 9;
            const int rem = tap - dz * 9;
            const int dy = rem / 3;
            const int dx = rem - dy * 3;
            const int slot = (dout + dz) & 3;
            const u16* bp = sm + ((size_t)(slot * 6 + wv + dy) * LROW + (mi + dx)) * 8;
#pragma unroll
            for (int t = 0; t < 8; ++t) {
                f16x8 act = *(const f16x8*)(bp + t * 128);  // +16 voxels
                acc[t] = __builtin_amdgcn_mfma_f32_16x16x32_f16(wf[s], act, acc[t], 0, 0, 0);
            }
        }

        // D: row(oc)=q*4+r, col(voxel)=mi -> lane stores 4 consecutive channels
        const size_t obase = ((size_t)(dout + 1) * P + (h0 + wv + 1)) * P + 1;
#pragma unroll
        for (int t = 0; t < 8; ++t) {
            uint2 o;
            o.x = pkh_relu(acc[t][0] + bv.x, acc[t][1] + bv.y);
            o.y = pkh_relu(acc[t][2] + bv.z, acc[t][3] + bv.w);
            *(uint2*)(x2 + (obase + 16 * t + mi) * 16 + q * 4) = o;
        }

        if (i < 7) __syncthreads();  // drains own DMAs (vmcnt) + publishes plane
    }
}

// conv3: padded x2 [130^3][16] f16 -> out fp32 [128^3] (one batch), tanh.
// 2(d) x 4(h) strip per thread (VOX/8 threads, 1024 blocks, 4 blocks/CU).
// SOFTWARE-PIPELINED: fully-unrolled 24-step (z,r) walk with ping-pong row
// buffers va/vb (6 uint4 each). Step k issues ALL 6 loads of row k+1 before
// computing row k -> ~6 loads always in flight per thread (round-2's VGPR=24
// build serialized each load-use chain; this is the fix for the ~50us stall).
#define LOADROW(V, zz, rr)                                            \
    do {                                                              \
        const u16* rp_ = xb + ((size_t)(zz)*PP + (size_t)(rr)*P) * 16;\
        V[0] = *(const uint4*)(rp_);                                  \
        V[1] = *(const uint4*)(rp_ + 8);                              \
        V[2] = *(const uint4*)(rp_ + 16);                             \
        V[3] = *(const uint4*)(rp_ + 24);                             \
        V[4] = *(const uint4*)(rp_ + 32);                             \
        V[5] = *(const uint4*)(rp_ + 40);                             \
    } while (0)

__global__ __launch_bounds__(256, 4) void conv3_kernel(
    const u16* __restrict__ x2, const unsigned* __restrict__ w3p,
    const float* __restrict__ b3, float* __restrict__ out) {
    const int t = blockIdx.x * 256 + threadIdx.x;  // VOX/8 threads
    const int w = t & 127;
    const int h0 = ((t >> 7) & 31) * 4;
    const int d0 = (t >> 12) * 2;

    const u16* xb = x2 + ((size_t)((d0)*P + h0) * P + w) * 16;

    float accA[2][4], accB[2][4];
#pragma unroll
    for (int dd = 0; dd < 2; ++dd)
#pragma unroll
        for (int i = 0; i < 4; ++i) { accA[dd][i] = 0.f; accB[dd][i] = 0.f; }

    uint4 va[6], vb[6];
    LOADROW(va, 0, 0);

#pragma unroll
    for (int step = 0; step < 24; ++step) {
        const int z = step / 6, r = step % 6;      // compile-time after unroll
        const int nz = (step + 1) / 6, nr = (step + 1) % 6;
        uint4* cur = (step & 1) ? vb : va;
        uint4* nxt = (step & 1) ? va : vb;
        if (step < 23) LOADROW(nxt, nz, nr);       // prefetch next row

#pragma unroll
        for (int dd = 0; dd < 2; ++dd) {
            const int dz = z - dd;
            if (dz < 0 || dz > 2) continue;        // compile-time
            const unsigned* wz = w3p + dz * 9 * 8;
#pragma unroll
            for (int dy = 0; dy < 3; ++dy) {
                const int i = r - dy;
                if (i < 0 || i > 3) continue;      // compile-time
                const unsigned* wp = wz + dy * 3 * 8;
                float a = accA[dd][i], b = accB[dd][i];
                a = dot2(cur[0].x, wp[0], a);  b = dot2(cur[0].y, wp[1], b);
                a = dot2(cur[0].z, wp[2], a);  b = dot2(cur[0].w, wp[3], b);
                a = dot2(cur[1].x, wp[4], a);  b = dot2(cur[1].y, wp[5], b);
                a = dot2(cur[1].z, wp[6], a);  b = dot2(cur[1].w, wp[7], b);
                a = dot2(cur[2].x, wp[8], a);  b = dot2(cur[2].y, wp[9], b);
                a = dot2(cur[2].z, wp[10], a); b = dot2(cur[2].w, wp[11], b);
                a = dot2(cur[3].x, wp[12], a); b = dot2(cur[3].y, wp[13], b);
                a = dot2(cur[3].z, wp[14], a); b = dot2(cur[3].w, wp[15], b);
                a = dot2(cur[4].x, wp[16], a); b = dot2(cur[4].y, wp[17], b);
                a = dot2(cur[4].z, wp[18], a); b = dot2(cur[4].w, wp[19], b);
                a = dot2(cur[5].x, wp[20], a); b = dot2(cur[5].y, wp[21], b);
                a = dot2(cur[5].z, wp[22], a); b = dot2(cur[5].w, wp[23], b);
                accA[dd][i] = a; accB[dd][i] = b;
            }
        }
    }
    const float bias = b3[0];
#pragma unroll
    for (int dd = 0; dd < 2; ++dd) {
        const size_t obase = (size_t)((d0 + dd) * 128 + h0) * 128 + w;
#pragma unroll
        for (int i = 0; i < 4; ++i)
            out[obase + (size_t)i * 128] = fast_tanh(accA[dd][i] + accB[dd][i] + bias);
    }
}

extern "C" void kernel_launch(void* const* d_in, const int* in_sizes, int n_in,
                              void* d_out, int out_size, void* d_ws, size_t ws_size,
                              hipStream_t stream) {
    const float* cube = (const float*)d_in[0];
    const float* w1 = (const float*)d_in[1];
    const float* b1 = (const float*)d_in[2];
    const float* w2 = (const float*)d_in[3];
    const float* b2 = (const float*)d_in[4];
    const float* w3 = (const float*)d_in[5];
    const float* b3 = (const float*)d_in[6];
    float* out = (float*)d_out;

    // ws: w2frag@0 (7168B) | w3p@7168 (864B) | w1c@8032 (864B) | x0 @16384 | x1 | x2
    char* ws = (char*)d_ws;
    u16* w2frag = (u16*)ws;
    unsigned* w3p = (unsigned*)(ws + 7168);
    float* w1c = (float*)(ws + 8032);
    u16* x0 = (u16*)(ws + 16384);
    u16* x1 = (u16*)(ws + 16384 + (size_t)PVOX * sizeof(u16));
    u16* x2 = (u16*)(ws + 16384 + (size_t)PVOX * sizeof(u16) + (size_t)PVOX * 8 * sizeof(u16));

    for (int b = 0; b < 2; ++b) {
        if (b == 0) {
            integrate_kernel<<<dim3((PVOX + 255) / 256), dim3(256), 0, stream>>>(
                cube, x0, w1, w2, w3, w2frag, w3p, w1c, x1, x2);
        } else {
            integrate_light_kernel<<<dim3(VOX / 256), dim3(256), 0, stream>>>(
                cube + (size_t)VOX, x0);
        }
        conv1_kernel<<<dim3(VOX / 8 / 256), dim3(256), 0, stream>>>(x0, w1c, b1, x1);
        conv2_mfma_kernel<<<dim3(512), dim3(256), 0, stream>>>(x1, w2frag, b2, x2);
        conv3_kernel<<<dim3(VOX / 8 / 256), dim3(256), 0, stream>>>(
            x2, w3p, b3, out + (size_t)b * VOX);
    }
}

// Round 6
// 245.349 us; speedup vs baseline: 3.4886x; 3.4886x over previous
//
#include <hip/hip_runtime.h>
#include <hip/hip_fp16.h>

#define VOX (128 * 128 * 128)   // 2097152
#define P 130                   // padded dim
#define PP (P * P)              // 16900
#define PVOX (P * P * P)        // 2197000
#define LROW 130
#define PLANE (6 * LROW)        // 780 16B-units per staged dz-plane

typedef unsigned short u16;
typedef _Float16 f16x2 __attribute__((ext_vector_type(2)));
typedef _Float16 f16x8 __attribute__((ext_vector_type(8)));
typedef __attribute__((ext_vector_type(4))) float f32x4;

__device__ __forceinline__ u16 f2h(float f) {
    return __builtin_bit_cast(unsigned short, (_Float16)f);
}
__device__ __forceinline__ unsigned pkh_relu(float a, float b) {
    float ra = a > 0.f ? a : 0.f, rb = b > 0.f ? b : 0.f;
    return (unsigned)f2h(ra) | ((unsigned)f2h(rb) << 16);
}
__device__ __forceinline__ f16x2 h2(unsigned u) { return __builtin_bit_cast(f16x2, u); }

// dot2: acc += a.x*b.x + a.y*b.y  (f32 accumulate, single V_DOT2_F32_F16)
__device__ __forceinline__ float dot2(unsigned a, unsigned b, float c) {
#if __has_builtin(__builtin_amdgcn_fdot2)
    return __builtin_amdgcn_fdot2(h2(a), h2(b), c, false);
#else
    f16x2 av = h2(a), bv = h2(b);
    c = fmaf((float)av.x, (float)bv.x, c);
    return fmaf((float)av.y, (float)bv.y, c);
#endif
}

// fast tanh: 1 - 2/(1+e^{2x})
__device__ __forceinline__ float fast_tanh(float x) {
    float e = __expf(2.0f * x);
    return 1.0f - 2.0f * __builtin_amdgcn_rcpf(1.0f + e);
}

// async global->LDS DMA, 16B per lane. LDS dest = wave-uniform base + lane*16.
__device__ __forceinline__ void gload_lds16(const u16* g, u16* l) {
    __builtin_amdgcn_global_load_lds(
        (const __attribute__((address_space(1))) unsigned int*)g,
        (__attribute__((address_space(3))) unsigned int*)l,
        16, 0, 0);
}

// heavy integrate (batch 0 only): x0 full (incl halo), weight prep, halo zeroing.
//  x0 padded f16 [130^3] = cube * (1 + 0.1*sin(2pi*(d+h+w)/384)), halo = 0
//  zero halo shells of x1 (8ch) / x2 (16ch)
//  w2frag[(s*64+lane)*8+j] = f16(w2[oc=lane&15][ic=j][tap=s*4+(lane>>4)]), 0 if tap>26
//  w3p[tap*8+j] = packed f16 pair (w3[2j][tap], w3[2j+1][tap])
//  w1c[tap*8+c] = f32 w1[c][tap]   (channel-contiguous for conv1 scalar FMA)
__global__ __launch_bounds__(256) void integrate_kernel(
    const float* __restrict__ in, u16* __restrict__ x0,
    const float* __restrict__ w1, const float* __restrict__ w2,
    const float* __restrict__ w3, u16* __restrict__ w2frag,
    unsigned* __restrict__ w3p, float* __restrict__ w1c,
    u16* __restrict__ x1, u16* __restrict__ x2) {
    int i = blockIdx.x * 256 + threadIdx.x;
    if (i < 3584) {
        int j = i & 7, l = (i >> 3) & 63, s = i >> 9;
        int tap = s * 4 + (l >> 4), oc = l & 15;
        float v = (tap < 27) ? w2[(oc * 8 + j) * 27 + tap] : 0.0f;
        w2frag[i] = f2h(v);
    }
    if (i < 216) {
        int tap = i >> 3, j = i & 7;
        w3p[i] = (unsigned)f2h(w3[(2 * j) * 27 + tap]) |
                 ((unsigned)f2h(w3[(2 * j + 1) * 27 + tap]) << 16);
        // w1c: tap-major, 8 channels contiguous
        int c = i & 7;
        w1c[i] = w1[c * 27 + tap];
    }
    if (i >= PVOX) return;
    int d = i / PP;
    int r = i - d * PP;
    int h = r / P;
    int w = r - h * P;
    const bool interior = (d >= 1 && d <= 128 && h >= 1 && h <= 128 && w >= 1 && w <= 128);
    float v = 0.0f;
    if (interior) {
        int s = (d - 1) + (h - 1) + (w - 1);
        float fld = 1.0f + 0.1f * __sinf(6.283185307179586f * (float)s / 384.0f);
        v = in[(size_t)(d - 1) * 16384 + (h - 1) * 128 + (w - 1)] * fld;
    } else {
        uint4 z = {0u, 0u, 0u, 0u};
        *(uint4*)(x1 + (size_t)i * 8) = z;
        *(uint4*)(x2 + (size_t)i * 16) = z;
        *(uint4*)(x2 + (size_t)i * 16 + 8) = z;
    }
    x0[i] = f2h(v);
}

// light integrate (batch 1): x0 interior only (halo already zero; prep idempotent)
__global__ __launch_bounds__(256) void integrate_light_kernel(
    const float* __restrict__ in, u16* __restrict__ x0) {
    const int i = blockIdx.x * 256 + threadIdx.x;  // VOX threads exactly
    const int d = i >> 14, h = (i >> 7) & 127, w = i & 127;
    const int s = d + h + w;
    const float fld = 1.0f + 0.1f * __sinf((float)s * 0.016362461737446838f);
    x0[(size_t)(d + 1) * PP + (h + 1) * P + (w + 1)] = f2h(in[i] * fld);
}

// conv1: x0 padded f16 [130^3] -> x1 f16 channels-last padded [130^3][8], relu.
// Strip 4(h) x 2(w) voxels/thread. SCALAR-FMA form: acc as 64 flat floats,
// weights via wave-uniform constant-offset loads (SGPR-resident s_load),
// acts as 4 scalar floats -> each FMA is one v_fmac_f32 (sgpr, vgpr), no
// operand-vector rebuild movs. 1728 fma/thread is the floor.
__global__ __launch_bounds__(256) void conv1_kernel(
    const u16* __restrict__ x0, const float* __restrict__ w1c,
    const float* __restrict__ b1, u16* __restrict__ x1) {
    const int t = blockIdx.x * 256 + threadIdx.x;  // VOX/8 threads
    const int w0 = (t & 63) * 2;
    const int h0 = ((t >> 6) & 31) * 4;
    const int d = t >> 11;

    float acc[4][2][8];  // [i(h)][m(w)][c]
#pragma unroll
    for (int c = 0; c < 8; ++c) {
        const float b = b1[c];
#pragma unroll
        for (int i = 0; i < 4; ++i) { acc[i][0][c] = b; acc[i][1][c] = b; }
    }

#pragma unroll
    for (int dz = 0; dz < 3; ++dz) {
        const u16* zb = x0 + (size_t)(d + dz) * PP + (size_t)h0 * P + w0;
        const float* wz = w1c + dz * 9 * 8;  // 72 floats, uniform const offsets
#pragma unroll
        for (int r = 0; r < 6; ++r) {
            const u16* rp = zb + r * P;
            const unsigned u0 = *(const unsigned*)rp;
            const unsigned u1 = *(const unsigned*)(rp + 2);
            float vv[4];
            vv[0] = (float)h2(u0).x; vv[1] = (float)h2(u0).y;
            vv[2] = (float)h2(u1).x; vv[3] = (float)h2(u1).y;
#pragma unroll
            for (int dy = 0; dy < 3; ++dy) {
                const int i = r - dy;
                if (i < 0 || i > 3) continue;  // resolved at compile time
#pragma unroll
                for (int dx = 0; dx < 3; ++dx) {
                    const float a0 = vv[dx];
                    const float a1 = vv[dx + 1];
                    const float* wp = wz + (dy * 3 + dx) * 8;
#pragma unroll
                    for (int c = 0; c < 8; ++c) {
                        const float wt = wp[c];
                        acc[i][0][c] = fmaf(wt, a0, acc[i][0][c]);
                        acc[i][1][c] = fmaf(wt, a1, acc[i][1][c]);
                    }
                }
            }
        }
    }
    const size_t e0 = ((size_t)(d + 1) * P + (h0 + 1)) * P + (w0 + 1);
#pragma unroll
    for (int i = 0; i < 4; ++i) {
        uint4 oA, oB;
        oA.x = pkh_relu(acc[i][0][0], acc[i][0][1]);
        oA.y = pkh_relu(acc[i][0][2], acc[i][0][3]);
        oA.z = pkh_relu(acc[i][0][4], acc[i][0][5]);
        oA.w = pkh_relu(acc[i][0][6], acc[i][0][7]);
        oB.x = pkh_relu(acc[i][1][0], acc[i][1][1]);
        oB.y = pkh_relu(acc[i][1][2], acc[i][1][3]);
        oB.z = pkh_relu(acc[i][1][4], acc[i][1][5]);
        oB.w = pkh_relu(acc[i][1][6], acc[i][1][7]);
        *(uint4*)(x1 + (e0 + (size_t)i * P) * 8) = oA;
        *(uint4*)(x1 + (e0 + (size_t)i * P + 1) * 8) = oB;
    }
}

// conv2: rolling-d LDS-staged implicit-GEMM MFMA, async DMA staging.
// d-chunk = 8 -> grid 512 blocks = 2/CU, ALL resident (cap 3/CU at 49.9KB):
// zero occupancy-quantization tail. One barrier per d-step.
__global__ __launch_bounds__(256) void conv2_mfma_kernel(
    const u16* __restrict__ x1, const u16* __restrict__ w2frag,
    const float* __restrict__ b2, u16* __restrict__ x2) {
    __shared__ u16 sm[4 * PLANE * 8];  // 49920 B

    const int tid = threadIdx.x;
    const int lane = tid & 63;
    const int wv = tid >> 6;  // output h-row offset 0..3
    const int q = lane >> 4;
    const int mi = lane & 15;
    const int D0 = (blockIdx.x >> 5) * 8;   // d-chunk base (unpadded out d)
    const int h0 = (blockIdx.x & 31) * 4;   // h-tile base

    // weight A-frags (7KB table, L1-resident)
    f16x8 wf[7];
#pragma unroll
    for (int s = 0; s < 7; ++s)
        wf[s] = *(const f16x8*)(w2frag + (size_t)(s * 64 + lane) * 8);

    // async stage planes D0..D0+2 (padded plane index pd covers rows h0..h0+5)
#pragma unroll
    for (int p = 0; p < 3; ++p) {
        const int pd = D0 + p;
        const int slot = pd & 3;
        const u16* gb = x1 + ((size_t)(pd * P + h0) * P) * 8;
        u16* lb = sm + (size_t)slot * PLANE * 8;
#pragma unroll
        for (int k = 0; k < 3; ++k) {
            const int u0 = wv * 64 + k * 256;
            gload_lds16(gb + (size_t)(u0 + lane) * 8, lb + (size_t)u0 * 8);
        }
        if (wv == 0 && lane < PLANE - 768)
            gload_lds16(gb + (size_t)(768 + lane) * 8, lb + (size_t)768 * 8);
    }
    __syncthreads();

    const float4 bv = *(const float4*)(b2 + q * 4);

#pragma unroll 1
    for (int i = 0; i < 8; ++i) {
        const int dout = D0 + i;

        // async prefetch plane dout+3 into its ring slot (unread this step)
        if (i < 7) {
            const int pd = dout + 3;
            const int slot = pd & 3;
            const u16* gb = x1 + ((size_t)(pd * P + h0) * P) * 8;
            u16* lb = sm + (size_t)slot * PLANE * 8;
#pragma unroll
            for (int k = 0; k < 3; ++k) {
                const int u0 = wv * 64 + k * 256;
                gload_lds16(gb + (size_t)(u0 + lane) * 8, lb + (size_t)u0 * 8);
            }
            if (wv == 0 && lane < PLANE - 768)
                gload_lds16(gb + (size_t)(768 + lane) * 8, lb + (size_t)768 * 8);
        }

        // compute output plane dout from slots (dout..dout+2)&3
        f32x4 acc[8];
#pragma unroll
        for (int t = 0; t < 8; ++t) acc[t] = (f32x4){0.f, 0.f, 0.f, 0.f};

#pragma unroll
        for (int s = 0; s < 7; ++s) {
            int tap = s * 4 + q;
            if (tap > 26) tap = 26;  // pad tap: weight frag is zero there
            const int dz = tap / 9;
            const int rem = tap - dz * 9;
            const int dy = rem / 3;
            const int dx = rem - dy * 3;
            const int slot = (dout + dz) & 3;
            const u16* bp = sm + ((size_t)(slot * 6 + wv + dy) * LROW + (mi + dx)) * 8;
#pragma unroll
            for (int t = 0; t < 8; ++t) {
                f16x8 act = *(const f16x8*)(bp + t * 128);  // +16 voxels
                acc[t] = __builtin_amdgcn_mfma_f32_16x16x32_f16(wf[s], act, acc[t], 0, 0, 0);
            }
        }

        // D: row(oc)=q*4+r, col(voxel)=mi -> lane stores 4 consecutive channels
        const size_t obase = ((size_t)(dout + 1) * P + (h0 + wv + 1)) * P + 1;
#pragma unroll
        for (int t = 0; t < 8; ++t) {
            uint2 o;
            o.x = pkh_relu(acc[t][0] + bv.x, acc[t][1] + bv.y);
            o.y = pkh_relu(acc[t][2] + bv.z, acc[t][3] + bv.w);
            *(uint2*)(x2 + (obase + 16 * t + mi) * 16 + q * 4) = o;
        }

        if (i < 7) __syncthreads();  // drains own DMAs (vmcnt) + publishes plane
    }
}

// conv3: padded x2 [130^3][16] f16 -> out fp32 [128^3] (one batch), tanh.
// 2(d) x 4(h) strip per thread (VOX/8 threads, 1024 blocks).
// SOFTWARE-PIPELINED ping-pong with NAMED uint4 scalars (va0..va5/vb0..vb5)
// and 24 lexically-expanded steps -> zero runtime indexing, no pointer
// selects (round 5's `cur = cond ? vb : va` forced scratch: 410MB spill
// writes). Step k issues all 6 loads of row k+1 before computing row k.
#define LR(V0, V1, V2, V3, V4, V5, zz, rr)                                 \
    do {                                                                   \
        const u16* rp_ = xb + ((size_t)(zz) * PP + (size_t)(rr) * P) * 16; \
        V0 = *(const uint4*)(rp_);                                         \
        V1 = *(const uint4*)(rp_ + 8);                                     \
        V2 = *(const uint4*)(rp_ + 16);                                    \
        V3 = *(const uint4*)(rp_ + 24);                                    \
        V4 = *(const uint4*)(rp_ + 32);                                    \
        V5 = *(const uint4*)(rp_ + 40);                                    \
    } while (0)

#define CMP(V0, V1, V2, V3, V4, V5, zz, rr)                                \
    do {                                                                   \
        _Pragma("unroll") for (int dd = 0; dd < 2; ++dd) {                 \
            const int dz = (zz)-dd;                                        \
            if (dz < 0 || dz > 2) continue; /* compile-time */             \
            const unsigned* wz = w3p + dz * 72;                            \
            _Pragma("unroll") for (int dy = 0; dy < 3; ++dy) {             \
                const int i = (rr)-dy;                                     \
                if (i < 0 || i > 3) continue; /* compile-time */           \
                const unsigned* wp = wz + dy * 24;                         \
                float a = accA[dd][i], b = accB[dd][i];                    \
                a = dot2(V0.x, wp[0], a);  b = dot2(V0.y, wp[1], b);       \
                a = dot2(V0.z, wp[2], a);  b = dot2(V0.w, wp[3], b);       \
                a = dot2(V1.x, wp[4], a);  b = dot2(V1.y, wp[5], b);       \
                a = dot2(V1.z, wp[6], a);  b = dot2(V1.w, wp[7], b);       \
                a = dot2(V2.x, wp[8], a);  b = dot2(V2.y, wp[9], b);       \
                a = dot2(V2.z, wp[10], a); b = dot2(V2.w, wp[11], b);      \
                a = dot2(V3.x, wp[12], a); b = dot2(V3.y, wp[13], b);      \
                a = dot2(V3.z, wp[14], a); b = dot2(V3.w, wp[15], b);      \
                a = dot2(V4.x, wp[16], a); b = dot2(V4.y, wp[17], b);      \
                a = dot2(V4.z, wp[18], a); b = dot2(V4.w, wp[19], b);      \
                a = dot2(V5.x, wp[20], a); b = dot2(V5.y, wp[21], b);      \
                a = dot2(V5.z, wp[22], a); b = dot2(V5.w, wp[23], b);      \
                accA[dd][i] = a; accB[dd][i] = b;                          \
            }                                                              \
        }                                                                  \
    } while (0)

// STEPA: compute va row (z,r), prefetch (nz,nr) into vb. STEPB: swapped.
#define STEPA(z, r, nz, nr)                           \
    do {                                              \
        LR(vb0, vb1, vb2, vb3, vb4, vb5, nz, nr);     \
        CMP(va0, va1, va2, va3, va4, va5, z, r);      \
    } while (0)
#define STEPB(z, r, nz, nr)                           \
    do {                                              \
        LR(va0, va1, va2, va3, va4, va5, nz, nr);     \
        CMP(vb0, vb1, vb2, vb3, vb4, vb5, z, r);      \
    } while (0)

__global__ __launch_bounds__(256) void conv3_kernel(
    const u16* __restrict__ x2, const unsigned* __restrict__ w3p,
    const float* __restrict__ b3, float* __restrict__ out) {
    const int t = blockIdx.x * 256 + threadIdx.x;  // VOX/8 threads
    const int w = t & 127;
    const int h0 = ((t >> 7) & 31) * 4;
    const int d0 = (t >> 12) * 2;

    const u16* xb = x2 + ((size_t)(d0 * P + h0) * P + w) * 16;

    float accA[2][4], accB[2][4];
#pragma unroll
    for (int dd = 0; dd < 2; ++dd)
#pragma unroll
        for (int i = 0; i < 4; ++i) { accA[dd][i] = 0.f; accB[dd][i] = 0.f; }

    uint4 va0, va1, va2, va3, va4, va5;
    uint4 vb0, vb1, vb2, vb3, vb4, vb5;

    LR(va0, va1, va2, va3, va4, va5, 0, 0);
    STEPA(0, 0, 0, 1); STEPB(0, 1, 0, 2); STEPA(0, 2, 0, 3); STEPB(0, 3, 0, 4);
    STEPA(0, 4, 0, 5); STEPB(0, 5, 1, 0); STEPA(1, 0, 1, 1); STEPB(1, 1, 1, 2);
    STEPA(1, 2, 1, 3); STEPB(1, 3, 1, 4); STEPA(1, 4, 1, 5); STEPB(1, 5, 2, 0);
    STEPA(2, 0, 2, 1); STEPB(2, 1, 2, 2); STEPA(2, 2, 2, 3); STEPB(2, 3, 2, 4);
    STEPA(2, 4, 2, 5); STEPB(2, 5, 3, 0); STEPA(3, 0, 3, 1); STEPB(3, 1, 3, 2);
    STEPA(3, 2, 3, 3); STEPB(3, 3, 3, 4); STEPA(3, 4, 3, 5);
    CMP(vb0, vb1, vb2, vb3, vb4, vb5, 3, 5);  // final row, no prefetch

    const float bias = b3[0];
#pragma unroll
    for (int dd = 0; dd < 2; ++dd) {
        const size_t obase = (size_t)((d0 + dd) * 128 + h0) * 128 + w;
#pragma unroll
        for (int i = 0; i < 4; ++i)
            out[obase + (size_t)i * 128] = fast_tanh(accA[dd][i] + accB[dd][i] + bias);
    }
}

extern "C" void kernel_launch(void* const* d_in, const int* in_sizes, int n_in,
                              void* d_out, int out_size, void* d_ws, size_t ws_size,
                              hipStream_t stream) {
    const float* cube = (const float*)d_in[0];
    const float* w1 = (const float*)d_in[1];
    const float* b1 = (const float*)d_in[2];
    const float* w2 = (const float*)d_in[3];
    const float* b2 = (const float*)d_in[4];
    const float* w3 = (const float*)d_in[5];
    const float* b3 = (const float*)d_in[6];
    float* out = (float*)d_out;

    // ws: w2frag@0 (7168B) | w3p@7168 (864B) | w1c@8032 (864B) | x0 @16384 | x1 | x2
    char* ws = (char*)d_ws;
    u16* w2frag = (u16*)ws;
    unsigned* w3p = (unsigned*)(ws + 7168);
    float* w1c = (float*)(ws + 8032);
    u16* x0 = (u16*)(ws + 16384);
    u16* x1 = (u16*)(ws + 16384 + (size_t)PVOX * sizeof(u16));
    u16* x2 = (u16*)(ws + 16384 + (size_t)PVOX * sizeof(u16) + (size_t)PVOX * 8 * sizeof(u16));

    for (int b = 0; b < 2; ++b) {
        if (b == 0) {
            integrate_kernel<<<dim3((PVOX + 255) / 256), dim3(256), 0, stream>>>(
                cube, x0, w1, w2, w3, w2frag, w3p, w1c, x1, x2);
        } else {
            integrate_light_kernel<<<dim3(VOX / 256), dim3(256), 0, stream>>>(
                cube + (size_t)VOX, x0);
        }
        conv1_kernel<<<dim3(VOX / 8 / 256), dim3(256), 0, stream>>>(x0, w1c, b1, x1);
        conv2_mfma_kernel<<<dim3(512), dim3(256), 0, stream>>>(x1, w2frag, b2, x2);
        conv3_kernel<<<dim3(VOX / 8 / 256), dim3(256), 0, stream>>>(
            x2, w3p, b3, out + (size_t)b * VOX);
    }
}

// Round 7
// 234.901 us; speedup vs baseline: 3.6438x; 1.0445x over previous
//
#include <hip/hip_runtime.h>
#include <hip/hip_fp16.h>

#define VOX (128 * 128 * 128)   // 2097152
#define P 130                   // padded dim
#define PP (P * P)              // 16900
#define PVOX (P * P * P)        // 2197000
#define LROW 130
#define PLANE (6 * LROW)        // 780 16B-units per staged dz-plane (conv2)
#define C3PLANE 1560            // 16B-units per staged conv3 plane (6*130 voxels * 32B)

typedef unsigned short u16;
typedef _Float16 f16x2 __attribute__((ext_vector_type(2)));
typedef _Float16 f16x8 __attribute__((ext_vector_type(8)));
typedef __attribute__((ext_vector_type(4))) float f32x4;

__device__ __forceinline__ u16 f2h(float f) {
    return __builtin_bit_cast(unsigned short, (_Float16)f);
}
__device__ __forceinline__ unsigned pkh_relu(float a, float b) {
    float ra = a > 0.f ? a : 0.f, rb = b > 0.f ? b : 0.f;
    return (unsigned)f2h(ra) | ((unsigned)f2h(rb) << 16);
}
__device__ __forceinline__ f16x2 h2(unsigned u) { return __builtin_bit_cast(f16x2, u); }

// dot2: acc += a.x*b.x + a.y*b.y  (f32 accumulate, single V_DOT2_F32_F16)
__device__ __forceinline__ float dot2(unsigned a, unsigned b, float c) {
#if __has_builtin(__builtin_amdgcn_fdot2)
    return __builtin_amdgcn_fdot2(h2(a), h2(b), c, false);
#else
    f16x2 av = h2(a), bv = h2(b);
    c = fmaf((float)av.x, (float)bv.x, c);
    return fmaf((float)av.y, (float)bv.y, c);
#endif
}

// fast tanh: 1 - 2/(1+e^{2x})
__device__ __forceinline__ float fast_tanh(float x) {
    float e = __expf(2.0f * x);
    return 1.0f - 2.0f * __builtin_amdgcn_rcpf(1.0f + e);
}

// async global->LDS DMA, 16B per lane. LDS dest = wave-uniform base + lane*16.
__device__ __forceinline__ void gload_lds16(const u16* g, u16* l) {
    __builtin_amdgcn_global_load_lds(
        (const __attribute__((address_space(1))) unsigned int*)g,
        (__attribute__((address_space(3))) unsigned int*)l,
        16, 0, 0);
}

// heavy integrate (batch 0 only): x0 full (incl halo), weight prep, halo zeroing.
//  x0 padded f16 [130^3] = cube * (1 + 0.1*sin(2pi*(d+h+w)/384)), halo = 0
//  zero halo shells of x1 (8ch) / x2 (16ch)
//  w2frag[(s*64+lane)*8+j] = f16(w2[oc=lane&15][ic=j][tap=s*4+(lane>>4)]), 0 if tap>26
//  w3p[tap*8+j] = packed f16 pair (w3[2j][tap], w3[2j+1][tap])
//  w1c[tap*8+c] = f32 w1[c][tap]   (channel-contiguous for conv1 scalar FMA)
__global__ __launch_bounds__(256) void integrate_kernel(
    const float* __restrict__ in, u16* __restrict__ x0,
    const float* __restrict__ w1, const float* __restrict__ w2,
    const float* __restrict__ w3, u16* __restrict__ w2frag,
    unsigned* __restrict__ w3p, float* __restrict__ w1c,
    u16* __restrict__ x1, u16* __restrict__ x2) {
    int i = blockIdx.x * 256 + threadIdx.x;
    if (i < 3584) {
        int j = i & 7, l = (i >> 3) & 63, s = i >> 9;
        int tap = s * 4 + (l >> 4), oc = l & 15;
        float v = (tap < 27) ? w2[(oc * 8 + j) * 27 + tap] : 0.0f;
        w2frag[i] = f2h(v);
    }
    if (i < 216) {
        int tap = i >> 3, j = i & 7;
        w3p[i] = (unsigned)f2h(w3[(2 * j) * 27 + tap]) |
                 ((unsigned)f2h(w3[(2 * j + 1) * 27 + tap]) << 16);
        // w1c: tap-major, 8 channels contiguous
        int c = i & 7;
        w1c[i] = w1[c * 27 + tap];
    }
    if (i >= PVOX) return;
    int d = i / PP;
    int r = i - d * PP;
    int h = r / P;
    int w = r - h * P;
    const bool interior = (d >= 1 && d <= 128 && h >= 1 && h <= 128 && w >= 1 && w <= 128);
    float v = 0.0f;
    if (interior) {
        int s = (d - 1) + (h - 1) + (w - 1);
        float fld = 1.0f + 0.1f * __sinf(6.283185307179586f * (float)s / 384.0f);
        v = in[(size_t)(d - 1) * 16384 + (h - 1) * 128 + (w - 1)] * fld;
    } else {
        uint4 z = {0u, 0u, 0u, 0u};
        *(uint4*)(x1 + (size_t)i * 8) = z;
        *(uint4*)(x2 + (size_t)i * 16) = z;
        *(uint4*)(x2 + (size_t)i * 16 + 8) = z;
    }
    x0[i] = f2h(v);
}

// light integrate (batch 1): x0 interior only (halo already zero; prep idempotent)
__global__ __launch_bounds__(256) void integrate_light_kernel(
    const float* __restrict__ in, u16* __restrict__ x0) {
    const int i = blockIdx.x * 256 + threadIdx.x;  // VOX threads exactly
    const int d = i >> 14, h = (i >> 7) & 127, w = i & 127;
    const int s = d + h + w;
    const float fld = 1.0f + 0.1f * __sinf((float)s * 0.016362461737446838f);
    x0[(size_t)(d + 1) * PP + (h + 1) * P + (w + 1)] = f2h(in[i] * fld);
}

// conv1: x0 padded f16 [130^3] -> x1 f16 channels-last padded [130^3][8], relu.
// Strip 4(h) x 2(w) voxels/thread. SCALAR-FMA form: acc as 64 flat floats,
// weights via wave-uniform constant-offset loads (SGPR-resident s_load),
// acts as 4 scalar floats -> each FMA is one v_fmac_f32 (sgpr, vgpr).
__global__ __launch_bounds__(256) void conv1_kernel(
    const u16* __restrict__ x0, const float* __restrict__ w1c,
    const float* __restrict__ b1, u16* __restrict__ x1) {
    const int t = blockIdx.x * 256 + threadIdx.x;  // VOX/8 threads
    const int w0 = (t & 63) * 2;
    const int h0 = ((t >> 6) & 31) * 4;
    const int d = t >> 11;

    float acc[4][2][8];  // [i(h)][m(w)][c]
#pragma unroll
    for (int c = 0; c < 8; ++c) {
        const float b = b1[c];
#pragma unroll
        for (int i = 0; i < 4; ++i) { acc[i][0][c] = b; acc[i][1][c] = b; }
    }

#pragma unroll
    for (int dz = 0; dz < 3; ++dz) {
        const u16* zb = x0 + (size_t)(d + dz) * PP + (size_t)h0 * P + w0;
        const float* wz = w1c + dz * 9 * 8;  // 72 floats, uniform const offsets
#pragma unroll
        for (int r = 0; r < 6; ++r) {
            const u16* rp = zb + r * P;
            const unsigned u0 = *(const unsigned*)rp;
            const unsigned u1 = *(const unsigned*)(rp + 2);
            float vv[4];
            vv[0] = (float)h2(u0).x; vv[1] = (float)h2(u0).y;
            vv[2] = (float)h2(u1).x; vv[3] = (float)h2(u1).y;
#pragma unroll
            for (int dy = 0; dy < 3; ++dy) {
                const int i = r - dy;
                if (i < 0 || i > 3) continue;  // resolved at compile time
#pragma unroll
                for (int dx = 0; dx < 3; ++dx) {
                    const float a0 = vv[dx];
                    const float a1 = vv[dx + 1];
                    const float* wp = wz + (dy * 3 + dx) * 8;
#pragma unroll
                    for (int c = 0; c < 8; ++c) {
                        const float wt = wp[c];
                        acc[i][0][c] = fmaf(wt, a0, acc[i][0][c]);
                        acc[i][1][c] = fmaf(wt, a1, acc[i][1][c]);
                    }
                }
            }
        }
    }
    const size_t e0 = ((size_t)(d + 1) * P + (h0 + 1)) * P + (w0 + 1);
#pragma unroll
    for (int i = 0; i < 4; ++i) {
        uint4 oA, oB;
        oA.x = pkh_relu(acc[i][0][0], acc[i][0][1]);
        oA.y = pkh_relu(acc[i][0][2], acc[i][0][3]);
        oA.z = pkh_relu(acc[i][0][4], acc[i][0][5]);
        oA.w = pkh_relu(acc[i][0][6], acc[i][0][7]);
        oB.x = pkh_relu(acc[i][1][0], acc[i][1][1]);
        oB.y = pkh_relu(acc[i][1][2], acc[i][1][3]);
        oB.z = pkh_relu(acc[i][1][4], acc[i][1][5]);
        oB.w = pkh_relu(acc[i][1][6], acc[i][1][7]);
        *(uint4*)(x1 + (e0 + (size_t)i * P) * 8) = oA;
        *(uint4*)(x1 + (e0 + (size_t)i * P + 1) * 8) = oB;
    }
}

// conv2: rolling-d LDS-staged implicit-GEMM MFMA, async DMA staging.
// d-chunk = 8 -> grid 512 blocks = 2/CU, ALL resident.
__global__ __launch_bounds__(256) void conv2_mfma_kernel(
    const u16* __restrict__ x1, const u16* __restrict__ w2frag,
    const float* __restrict__ b2, u16* __restrict__ x2) {
    __shared__ u16 sm[4 * PLANE * 8];  // 49920 B

    const int tid = threadIdx.x;
    const int lane = tid & 63;
    const int wv = tid >> 6;  // output h-row offset 0..3
    const int q = lane >> 4;
    const int mi = lane & 15;
    const int D0 = (blockIdx.x >> 5) * 8;   // d-chunk base (unpadded out d)
    const int h0 = (blockIdx.x & 31) * 4;   // h-tile base

    // weight A-frags (7KB table, L1-resident)
    f16x8 wf[7];
#pragma unroll
    for (int s = 0; s < 7; ++s)
        wf[s] = *(const f16x8*)(w2frag + (size_t)(s * 64 + lane) * 8);

    // async stage planes D0..D0+2 (padded plane index pd covers rows h0..h0+5)
#pragma unroll
    for (int p = 0; p < 3; ++p) {
        const int pd = D0 + p;
        const int slot = pd & 3;
        const u16* gb = x1 + ((size_t)(pd * P + h0) * P) * 8;
        u16* lb = sm + (size_t)slot * PLANE * 8;
#pragma unroll
        for (int k = 0; k < 3; ++k) {
            const int u0 = wv * 64 + k * 256;
            gload_lds16(gb + (size_t)(u0 + lane) * 8, lb + (size_t)u0 * 8);
        }
        if (wv == 0 && lane < PLANE - 768)
            gload_lds16(gb + (size_t)(768 + lane) * 8, lb + (size_t)768 * 8);
    }
    __syncthreads();

    const float4 bv = *(const float4*)(b2 + q * 4);

#pragma unroll 1
    for (int i = 0; i < 8; ++i) {
        const int dout = D0 + i;

        // async prefetch plane dout+3 into its ring slot (unread this step)
        if (i < 7) {
            const int pd = dout + 3;
            const int slot = pd & 3;
            const u16* gb = x1 + ((size_t)(pd * P + h0) * P) * 8;
            u16* lb = sm + (size_t)slot * PLANE * 8;
#pragma unroll
            for (int k = 0; k < 3; ++k) {
                const int u0 = wv * 64 + k * 256;
                gload_lds16(gb + (size_t)(u0 + lane) * 8, lb + (size_t)u0 * 8);
            }
            if (wv == 0 && lane < PLANE - 768)
                gload_lds16(gb + (size_t)(768 + lane) * 8, lb + (size_t)768 * 8);
        }

        // compute output plane dout from slots (dout..dout+2)&3
        f32x4 acc[8];
#pragma unroll
        for (int t = 0; t < 8; ++t) acc[t] = (f32x4){0.f, 0.f, 0.f, 0.f};

#pragma unroll
        for (int s = 0; s < 7; ++s) {
            int tap = s * 4 + q;
            if (tap > 26) tap = 26;  // pad tap: weight frag is zero there
            const int dz = tap / 9;
            const int rem = tap - dz * 9;
            const int dy = rem / 3;
            const int dx = rem - dy * 3;
            const int slot = (dout + dz) & 3;
            const u16* bp = sm + ((size_t)(slot * 6 + wv + dy) * LROW + (mi + dx)) * 8;
#pragma unroll
            for (int t = 0; t < 8; ++t) {
                f16x8 act = *(const f16x8*)(bp + t * 128);  // +16 voxels
                acc[t] = __builtin_amdgcn_mfma_f32_16x16x32_f16(wf[s], act, acc[t], 0, 0, 0);
            }
        }

        // D: row(oc)=q*4+r, col(voxel)=mi -> lane stores 4 consecutive channels
        const size_t obase = ((size_t)(dout + 1) * P + (h0 + wv + 1)) * P + 1;
#pragma unroll
        for (int t = 0; t < 8; ++t) {
            uint2 o;
            o.x = pkh_relu(acc[t][0] + bv.x, acc[t][1] + bv.y);
            o.y = pkh_relu(acc[t][2] + bv.z, acc[t][3] + bv.w);
            *(uint2*)(x2 + (obase + 16 * t + mi) * 16 + q * 4) = o;
        }

        if (i < 7) __syncthreads();  // drains own DMAs (vmcnt) + publishes plane
    }
}

// conv3: LDS-staged clone of conv2's ring (the async-DMA path has unbounded
// queue depth and zero VGPR cost -> latency-tolerant, unlike R4/R6 register
// pipelining). Grid 512 = 32 h-tiles x 16 d-chunks, 256 threads, 1 block/CU
// (99.8 KB LDS). Ring: 4 slots x [6 rows x 130 voxels x 32B] (globally
// contiguous -> same DMA pattern as conv2). Compute: lane pair (p=tid>>1,
// half=tid&1): even lane does ch0-7, odd ch8-15, for all 4 h-rows at w=p.
// LDS reads are 16B at stride-16 across lanes -> conflict-free; 432 B/voxel.
// All 108 w3 words preloaded to 27 uint4 regs (VGPR free at 1 block/CU).
// One shfl_xor(1) combines the channel halves.
__global__ __launch_bounds__(256, 1) void conv3_kernel(
    const u16* __restrict__ x2, const unsigned* __restrict__ w3p,
    const float* __restrict__ b3, float* __restrict__ out) {
    __shared__ u16 sm[4 * C3PLANE * 8];  // 99840 B

    const int tid = threadIdx.x;
    const int lane = tid & 63;
    const int wv = tid >> 6;
    const int half = tid & 1;
    const int p = tid >> 1;              // w coordinate 0..127
    const int D0 = (blockIdx.x >> 5) * 8;  // d-chunk base (unpadded out d)
    const int h0 = (blockIdx.x & 31) * 4;  // h-tile base

    // preload all 27 taps x 4 packed ch-pair words for this lane's half
    uint4 wt[27];
#pragma unroll
    for (int q = 0; q < 27; ++q)
        wt[q] = *(const uint4*)(w3p + q * 8 + half * 4);

    // stage planes D0..D0+2 (padded plane pd covers padded rows h0..h0+5,
    // 780 voxels = 1560 16B-units, globally contiguous)
#pragma unroll
    for (int pp = 0; pp < 3; ++pp) {
        const int pd = D0 + pp;
        const int slot = pd & 3;
        const u16* gb = x2 + ((size_t)(pd * P + h0) * P) * 16;
        u16* lb = sm + (size_t)slot * C3PLANE * 8;
#pragma unroll
        for (int k = 0; k < 6; ++k) {
            const int u0 = wv * 64 + k * 256;
            gload_lds16(gb + (size_t)(u0 + lane) * 8, lb + (size_t)u0 * 8);
        }
        if (wv == 0 && lane < C3PLANE - 1536)
            gload_lds16(gb + (size_t)(1536 + lane) * 8, lb + (size_t)1536 * 8);
    }
    __syncthreads();

    const float bias = b3[0];

#pragma unroll 1
    for (int i = 0; i < 8; ++i) {
        const int dout = D0 + i;

        // async prefetch plane dout+3 into its ring slot (unread this step)
        if (i < 7) {
            const int pd = dout + 3;
            const int slot = pd & 3;
            const u16* gb = x2 + ((size_t)(pd * P + h0) * P) * 16;
            u16* lb = sm + (size_t)slot * C3PLANE * 8;
#pragma unroll
            for (int k = 0; k < 6; ++k) {
                const int u0 = wv * 64 + k * 256;
                gload_lds16(gb + (size_t)(u0 + lane) * 8, lb + (size_t)u0 * 8);
            }
            if (wv == 0 && lane < C3PLANE - 1536)
                gload_lds16(gb + (size_t)(1536 + lane) * 8, lb + (size_t)1536 * 8);
        }

        float acc[4] = {0.f, 0.f, 0.f, 0.f};  // this half's sums, h-rows 0..3
#pragma unroll
        for (int dz = 0; dz < 3; ++dz) {      // fully unrolled: wt[] static idx
            const int slot = (dout + dz) & 3;
            const u16* sp = sm + (size_t)slot * C3PLANE * 8 + (size_t)half * 8;
#pragma unroll
            for (int r = 0; r < 6; ++r) {
                const u16* rp = sp + (size_t)(r * 130 + p) * 16;
                const uint4 v0 = *(const uint4*)(rp);
                const uint4 v1 = *(const uint4*)(rp + 16);
                const uint4 v2 = *(const uint4*)(rp + 32);
#pragma unroll
                for (int dy = 0; dy < 3; ++dy) {
                    const int ii = r - dy;
                    if (ii < 0 || ii > 3) continue;  // compile-time
#pragma unroll
                    for (int dx = 0; dx < 3; ++dx) {
                        const uint4 wq = wt[dz * 9 + dy * 3 + dx];
                        const uint4 v = (dx == 0) ? v0 : ((dx == 1) ? v1 : v2);
                        float a = acc[ii];
                        a = dot2(v.x, wq.x, a);
                        a = dot2(v.y, wq.y, a);
                        a = dot2(v.z, wq.z, a);
                        a = dot2(v.w, wq.w, a);
                        acc[ii] = a;
                    }
                }
            }
        }

        // combine halves: partner lane (lane^1) holds the other 8 channels
#pragma unroll
        for (int k = 0; k < 4; ++k) acc[k] += __shfl_xor(acc[k], 1);

        // each lane stores 2 of the 4 h-rows
        const size_t ob = ((size_t)dout * 128 + h0) * 128 + p;
#pragma unroll
        for (int k = 0; k < 2; ++k) {
            const int hr = half * 2 + k;
            out[ob + (size_t)hr * 128] = fast_tanh(acc[hr] + bias);
        }

        if (i < 7) __syncthreads();  // drains own DMAs + protects slot reuse
    }
}

extern "C" void kernel_launch(void* const* d_in, const int* in_sizes, int n_in,
                              void* d_out, int out_size, void* d_ws, size_t ws_size,
                              hipStream_t stream) {
    const float* cube = (const float*)d_in[0];
    const float* w1 = (const float*)d_in[1];
    const float* b1 = (const float*)d_in[2];
    const float* w2 = (const float*)d_in[3];
    const float* b2 = (const float*)d_in[4];
    const float* w3 = (const float*)d_in[5];
    const float* b3 = (const float*)d_in[6];
    float* out = (float*)d_out;

    // ws: w2frag@0 (7168B) | w3p@7168 (864B) | w1c@8032 (864B) | x0 @16384 | x1 | x2
    char* ws = (char*)d_ws;
    u16* w2frag = (u16*)ws;
    unsigned* w3p = (unsigned*)(ws + 7168);
    float* w1c = (float*)(ws + 8032);
    u16* x0 = (u16*)(ws + 16384);
    u16* x1 = (u16*)(ws + 16384 + (size_t)PVOX * sizeof(u16));
    u16* x2 = (u16*)(ws + 16384 + (size_t)PVOX * sizeof(u16) + (size_t)PVOX * 8 * sizeof(u16));

    for (int b = 0; b < 2; ++b) {
        if (b == 0) {
            integrate_kernel<<<dim3((PVOX + 255) / 256), dim3(256), 0, stream>>>(
                cube, x0, w1, w2, w3, w2frag, w3p, w1c, x1, x2);
        } else {
            integrate_light_kernel<<<dim3(VOX / 256), dim3(256), 0, stream>>>(
                cube + (size_t)VOX, x0);
        }
        conv1_kernel<<<dim3(VOX / 8 / 256), dim3(256), 0, stream>>>(x0, w1c, b1, x1);
        conv2_mfma_kernel<<<dim3(512), dim3(256), 0, stream>>>(x1, w2frag, b2, x2);
        conv3_kernel<<<dim3(512), dim3(256), 0, stream>>>(
            x2, w3p, b3, out + (size_t)b * VOX);
    }
}

// Round 8
// 228.865 us; speedup vs baseline: 3.7399x; 1.0264x over previous
//
#include <hip/hip_runtime.h>
#include <hip/hip_fp16.h>

#define VOX (128 * 128 * 128)   // 2097152
#define P 130                   // padded dim
#define PP (P * P)              // 16900
#define PVOX (P * P * P)        // 2197000
#define LROW 130
#define PLANE (6 * LROW)        // 780 16B-units per staged dz-plane (conv2)
#define C3PLANE 1560            // 16B-units per staged conv3 plane (6*130 voxels * 32B)

typedef unsigned short u16;
typedef _Float16 f16x2 __attribute__((ext_vector_type(2)));
typedef _Float16 f16x8 __attribute__((ext_vector_type(8)));
typedef __attribute__((ext_vector_type(4))) float f32x4;

__device__ __forceinline__ u16 f2h(float f) {
    return __builtin_bit_cast(unsigned short, (_Float16)f);
}
__device__ __forceinline__ unsigned pkh_relu(float a, float b) {
    float ra = a > 0.f ? a : 0.f, rb = b > 0.f ? b : 0.f;
    return (unsigned)f2h(ra) | ((unsigned)f2h(rb) << 16);
}
__device__ __forceinline__ f16x2 h2(unsigned u) { return __builtin_bit_cast(f16x2, u); }

// dot2: acc += a.x*b.x + a.y*b.y  (f32 accumulate, single V_DOT2_F32_F16)
__device__ __forceinline__ float dot2(unsigned a, unsigned b, float c) {
#if __has_builtin(__builtin_amdgcn_fdot2)
    return __builtin_amdgcn_fdot2(h2(a), h2(b), c, false);
#else
    f16x2 av = h2(a), bv = h2(b);
    c = fmaf((float)av.x, (float)bv.x, c);
    return fmaf((float)av.y, (float)bv.y, c);
#endif
}

// fast tanh: 1 - 2/(1+e^{2x})
__device__ __forceinline__ float fast_tanh(float x) {
    float e = __expf(2.0f * x);
    return 1.0f - 2.0f * __builtin_amdgcn_rcpf(1.0f + e);
}

// async global->LDS DMA, 16B per lane. LDS dest = wave-uniform base + lane*16.
__device__ __forceinline__ void gload_lds16(const u16* g, u16* l) {
    __builtin_amdgcn_global_load_lds(
        (const __attribute__((address_space(1))) unsigned int*)g,
        (__attribute__((address_space(3))) unsigned int*)l,
        16, 0, 0);
}

// heavy integrate (batch 0 only): x0 full (incl halo), weight prep, halo zeroing.
//  x0 padded f16 [130^3] = cube * (1 + 0.1*sin(2pi*(d+h+w)/384)), halo = 0
//  zero halo shells of x1 (8ch) / x2 (16ch)
//  w2frag[(s*64+lane)*8+j] = f16(w2[oc=lane&15][ic=j][tap=s*4+(lane>>4)]), 0 if tap>26
//  w3p[tap*8+j] = packed f16 pair (w3[2j][tap], w3[2j+1][tap])
//  w1c[tap*8+c] = f32 w1[c][tap]   (channel-contiguous for conv1 scalar FMA)
__global__ __launch_bounds__(256) void integrate_kernel(
    const float* __restrict__ in, u16* __restrict__ x0,
    const float* __restrict__ w1, const float* __restrict__ w2,
    const float* __restrict__ w3, u16* __restrict__ w2frag,
    unsigned* __restrict__ w3p, float* __restrict__ w1c,
    u16* __restrict__ x1, u16* __restrict__ x2) {
    int i = blockIdx.x * 256 + threadIdx.x;
    if (i < 3584) {
        int j = i & 7, l = (i >> 3) & 63, s = i >> 9;
        int tap = s * 4 + (l >> 4), oc = l & 15;
        float v = (tap < 27) ? w2[(oc * 8 + j) * 27 + tap] : 0.0f;
        w2frag[i] = f2h(v);
    }
    if (i < 216) {
        int tap = i >> 3, j = i & 7;
        w3p[i] = (unsigned)f2h(w3[(2 * j) * 27 + tap]) |
                 ((unsigned)f2h(w3[(2 * j + 1) * 27 + tap]) << 16);
        // w1c: tap-major, 8 channels contiguous
        int c = i & 7;
        w1c[i] = w1[c * 27 + tap];
    }
    if (i >= PVOX) return;
    int d = i / PP;
    int r = i - d * PP;
    int h = r / P;
    int w = r - h * P;
    const bool interior = (d >= 1 && d <= 128 && h >= 1 && h <= 128 && w >= 1 && w <= 128);
    float v = 0.0f;
    if (interior) {
        int s = (d - 1) + (h - 1) + (w - 1);
        float fld = 1.0f + 0.1f * __sinf(6.283185307179586f * (float)s / 384.0f);
        v = in[(size_t)(d - 1) * 16384 + (h - 1) * 128 + (w - 1)] * fld;
    } else {
        uint4 z = {0u, 0u, 0u, 0u};
        *(uint4*)(x1 + (size_t)i * 8) = z;
        *(uint4*)(x2 + (size_t)i * 16) = z;
        *(uint4*)(x2 + (size_t)i * 16 + 8) = z;
    }
    x0[i] = f2h(v);
}

// light integrate (batch 1): x0 interior only (halo already zero; prep idempotent)
__global__ __launch_bounds__(256) void integrate_light_kernel(
    const float* __restrict__ in, u16* __restrict__ x0) {
    const int i = blockIdx.x * 256 + threadIdx.x;  // VOX threads exactly
    const int d = i >> 14, h = (i >> 7) & 127, w = i & 127;
    const int s = d + h + w;
    const float fld = 1.0f + 0.1f * __sinf((float)s * 0.016362461737446838f);
    x0[(size_t)(d + 1) * PP + (h + 1) * P + (w + 1)] = f2h(in[i] * fld);
}

// conv1: x0 padded f16 [130^3] -> x1 f16 channels-last padded [130^3][8], relu.
// Strip 4(h) x 2(w) voxels/thread. SCALAR-FMA form: acc as 64 flat floats,
// weights via wave-uniform constant-offset loads (SGPR-resident s_load),
// acts as 4 scalar floats -> each FMA is one v_fmac_f32 (sgpr, vgpr).
__global__ __launch_bounds__(256) void conv1_kernel(
    const u16* __restrict__ x0, const float* __restrict__ w1c,
    const float* __restrict__ b1, u16* __restrict__ x1) {
    const int t = blockIdx.x * 256 + threadIdx.x;  // VOX/8 threads
    const int w0 = (t & 63) * 2;
    const int h0 = ((t >> 6) & 31) * 4;
    const int d = t >> 11;

    float acc[4][2][8];  // [i(h)][m(w)][c]
#pragma unroll
    for (int c = 0; c < 8; ++c) {
        const float b = b1[c];
#pragma unroll
        for (int i = 0; i < 4; ++i) { acc[i][0][c] = b; acc[i][1][c] = b; }
    }

#pragma unroll
    for (int dz = 0; dz < 3; ++dz) {
        const u16* zb = x0 + (size_t)(d + dz) * PP + (size_t)h0 * P + w0;
        const float* wz = w1c + dz * 9 * 8;  // 72 floats, uniform const offsets
#pragma unroll
        for (int r = 0; r < 6; ++r) {
            const u16* rp = zb + r * P;
            const unsigned u0 = *(const unsigned*)rp;
            const unsigned u1 = *(const unsigned*)(rp + 2);
            float vv[4];
            vv[0] = (float)h2(u0).x; vv[1] = (float)h2(u0).y;
            vv[2] = (float)h2(u1).x; vv[3] = (float)h2(u1).y;
#pragma unroll
            for (int dy = 0; dy < 3; ++dy) {
                const int i = r - dy;
                if (i < 0 || i > 3) continue;  // resolved at compile time
#pragma unroll
                for (int dx = 0; dx < 3; ++dx) {
                    const float a0 = vv[dx];
                    const float a1 = vv[dx + 1];
                    const float* wp = wz + (dy * 3 + dx) * 8;
#pragma unroll
                    for (int c = 0; c < 8; ++c) {
                        const float wt = wp[c];
                        acc[i][0][c] = fmaf(wt, a0, acc[i][0][c]);
                        acc[i][1][c] = fmaf(wt, a1, acc[i][1][c]);
                    }
                }
            }
        }
    }
    const size_t e0 = ((size_t)(d + 1) * P + (h0 + 1)) * P + (w0 + 1);
#pragma unroll
    for (int i = 0; i < 4; ++i) {
        uint4 oA, oB;
        oA.x = pkh_relu(acc[i][0][0], acc[i][0][1]);
        oA.y = pkh_relu(acc[i][0][2], acc[i][0][3]);
        oA.z = pkh_relu(acc[i][0][4], acc[i][0][5]);
        oA.w = pkh_relu(acc[i][0][6], acc[i][0][7]);
        oB.x = pkh_relu(acc[i][1][0], acc[i][1][1]);
        oB.y = pkh_relu(acc[i][1][2], acc[i][1][3]);
        oB.z = pkh_relu(acc[i][1][4], acc[i][1][5]);
        oB.w = pkh_relu(acc[i][1][6], acc[i][1][7]);
        *(uint4*)(x1 + (e0 + (size_t)i * P) * 8) = oA;
        *(uint4*)(x1 + (e0 + (size_t)i * P + 1) * 8) = oB;
    }
}

// conv2: rolling-d LDS-staged implicit-GEMM MFMA, async DMA staging.
// d-chunk = 8 -> grid 512 blocks = 2/CU, ALL resident.
__global__ __launch_bounds__(256) void conv2_mfma_kernel(
    const u16* __restrict__ x1, const u16* __restrict__ w2frag,
    const float* __restrict__ b2, u16* __restrict__ x2) {
    __shared__ u16 sm[4 * PLANE * 8];  // 49920 B

    const int tid = threadIdx.x;
    const int lane = tid & 63;
    const int wv = tid >> 6;  // output h-row offset 0..3
    const int q = lane >> 4;
    const int mi = lane & 15;
    const int D0 = (blockIdx.x >> 5) * 8;   // d-chunk base (unpadded out d)
    const int h0 = (blockIdx.x & 31) * 4;   // h-tile base

    // weight A-frags (7KB table, L1-resident)
    f16x8 wf[7];
#pragma unroll
    for (int s = 0; s < 7; ++s)
        wf[s] = *(const f16x8*)(w2frag + (size_t)(s * 64 + lane) * 8);

    // async stage planes D0..D0+2 (padded plane index pd covers rows h0..h0+5)
#pragma unroll
    for (int p = 0; p < 3; ++p) {
        const int pd = D0 + p;
        const int slot = pd & 3;
        const u16* gb = x1 + ((size_t)(pd * P + h0) * P) * 8;
        u16* lb = sm + (size_t)slot * PLANE * 8;
#pragma unroll
        for (int k = 0; k < 3; ++k) {
            const int u0 = wv * 64 + k * 256;
            gload_lds16(gb + (size_t)(u0 + lane) * 8, lb + (size_t)u0 * 8);
        }
        if (wv == 0 && lane < PLANE - 768)
            gload_lds16(gb + (size_t)(768 + lane) * 8, lb + (size_t)768 * 8);
    }
    __syncthreads();

    const float4 bv = *(const float4*)(b2 + q * 4);

#pragma unroll 1
    for (int i = 0; i < 8; ++i) {
        const int dout = D0 + i;

        // async prefetch plane dout+3 into its ring slot (unread this step)
        if (i < 7) {
            const int pd = dout + 3;
            const int slot = pd & 3;
            const u16* gb = x1 + ((size_t)(pd * P + h0) * P) * 8;
            u16* lb = sm + (size_t)slot * PLANE * 8;
#pragma unroll
            for (int k = 0; k < 3; ++k) {
                const int u0 = wv * 64 + k * 256;
                gload_lds16(gb + (size_t)(u0 + lane) * 8, lb + (size_t)u0 * 8);
            }
            if (wv == 0 && lane < PLANE - 768)
                gload_lds16(gb + (size_t)(768 + lane) * 8, lb + (size_t)768 * 8);
        }

        // compute output plane dout from slots (dout..dout+2)&3
        f32x4 acc[8];
#pragma unroll
        for (int t = 0; t < 8; ++t) acc[t] = (f32x4){0.f, 0.f, 0.f, 0.f};

#pragma unroll
        for (int s = 0; s < 7; ++s) {
            int tap = s * 4 + q;
            if (tap > 26) tap = 26;  // pad tap: weight frag is zero there
            const int dz = tap / 9;
            const int rem = tap - dz * 9;
            const int dy = rem / 3;
            const int dx = rem - dy * 3;
            const int slot = (dout + dz) & 3;
            const u16* bp = sm + ((size_t)(slot * 6 + wv + dy) * LROW + (mi + dx)) * 8;
#pragma unroll
            for (int t = 0; t < 8; ++t) {
                f16x8 act = *(const f16x8*)(bp + t * 128);  // +16 voxels
                acc[t] = __builtin_amdgcn_mfma_f32_16x16x32_f16(wf[s], act, acc[t], 0, 0, 0);
            }
        }

        // D: row(oc)=q*4+r, col(voxel)=mi -> lane stores 4 consecutive channels
        const size_t obase = ((size_t)(dout + 1) * P + (h0 + wv + 1)) * P + 1;
#pragma unroll
        for (int t = 0; t < 8; ++t) {
            uint2 o;
            o.x = pkh_relu(acc[t][0] + bv.x, acc[t][1] + bv.y);
            o.y = pkh_relu(acc[t][2] + bv.z, acc[t][3] + bv.w);
            *(uint2*)(x2 + (obase + 16 * t + mi) * 16 + q * 4) = o;
        }

        if (i < 7) __syncthreads();  // drains own DMAs (vmcnt) + publishes plane
    }
}

// conv3: LDS-ring staged (proven R7 DMA machinery) but 512 threads/block,
// d-chunk 16, grid 256 = exactly 1 block/CU in ONE round (R7's 256-thread
// 512-block config was 1 wave/SIMD x 2 sequential rounds -> latency-bound,
// 2.6us/step vs 0.72us LDS floor). Thread = (w-column p=tid>>2, channel
// quarter cq=tid&3): each thread reads only its 8B per voxel (b64, 512B
// contiguous per wave, conflict-free), 216 dot2/step; 4-lane shfl_xor
// all-reduce combines quarters -> per-CU LDS bytes unchanged, 2 waves/SIMD,
// VALU per wave halved. 27 x uint2 per-quarter weight preload (~54 VGPR).
__global__ __launch_bounds__(512, 1) void conv3_kernel(
    const u16* __restrict__ x2, const unsigned* __restrict__ w3p,
    const float* __restrict__ b3, float* __restrict__ out) {
    __shared__ u16 sm[4 * C3PLANE * 8];  // 99840 B

    const int tid = threadIdx.x;
    const int lane = tid & 63;
    const int wv = tid >> 6;               // 0..7
    const int cq = tid & 3;                // channel quarter (ch 4cq..4cq+3)
    const int p = tid >> 2;                // w coordinate 0..127
    const int D0 = (blockIdx.x >> 5) * 16; // d-chunk base (unpadded out d)
    const int h0 = (blockIdx.x & 31) * 4;  // h-tile base

    // preload 27 taps x this quarter's 2 packed ch-pair words
    uint2 wt[27];
#pragma unroll
    for (int q = 0; q < 27; ++q)
        wt[q] = *(const uint2*)(w3p + q * 8 + cq * 2);

    // stage planes D0..D0+2 (plane = padded rows h0..h0+5 x 130 vox x 32B,
    // globally contiguous; 1560 16B-units = 3 x 512 lanes + 24 remainder)
#pragma unroll
    for (int pp = 0; pp < 3; ++pp) {
        const int pd = D0 + pp;
        const int slot = pd & 3;
        const u16* gb = x2 + ((size_t)(pd * P + h0) * P) * 16;
        u16* lb = sm + (size_t)slot * C3PLANE * 8;
#pragma unroll
        for (int k = 0; k < 3; ++k) {
            const int u0 = wv * 64 + k * 512;
            gload_lds16(gb + (size_t)(u0 + lane) * 8, lb + (size_t)u0 * 8);
        }
        if (wv == 0 && lane < C3PLANE - 1536)
            gload_lds16(gb + (size_t)(1536 + lane) * 8, lb + (size_t)1536 * 8);
    }
    __syncthreads();

    const float bias = b3[0];

#pragma unroll 1
    for (int i = 0; i < 16; ++i) {
        const int dout = D0 + i;

        // async prefetch plane dout+3 into its ring slot (unread this step)
        if (i < 15) {
            const int pd = dout + 3;
            const int slot = pd & 3;
            const u16* gb = x2 + ((size_t)(pd * P + h0) * P) * 16;
            u16* lb = sm + (size_t)slot * C3PLANE * 8;
#pragma unroll
            for (int k = 0; k < 3; ++k) {
                const int u0 = wv * 64 + k * 512;
                gload_lds16(gb + (size_t)(u0 + lane) * 8, lb + (size_t)u0 * 8);
            }
            if (wv == 0 && lane < C3PLANE - 1536)
                gload_lds16(gb + (size_t)(1536 + lane) * 8, lb + (size_t)1536 * 8);
        }

        float acc[4] = {0.f, 0.f, 0.f, 0.f};  // h-rows 0..3, this quarter's sum
#pragma unroll
        for (int dz = 0; dz < 3; ++dz) {       // fully unrolled: wt[] static idx
            const int slot = (dout + dz) & 3;
            const u16* sp = sm + (size_t)slot * C3PLANE * 8 + (size_t)cq * 4;
#pragma unroll
            for (int r = 0; r < 6; ++r) {
                const u16* rp = sp + (size_t)(r * 130 + p) * 16;
                const uint2 v0 = *(const uint2*)(rp);
                const uint2 v1 = *(const uint2*)(rp + 16);
                const uint2 v2 = *(const uint2*)(rp + 32);
#pragma unroll
                for (int dy = 0; dy < 3; ++dy) {
                    const int ii = r - dy;
                    if (ii < 0 || ii > 3) continue;  // compile-time
                    const uint2 wq0 = wt[dz * 9 + dy * 3 + 0];
                    const uint2 wq1 = wt[dz * 9 + dy * 3 + 1];
                    const uint2 wq2 = wt[dz * 9 + dy * 3 + 2];
                    float a = acc[ii];
                    a = dot2(v0.x, wq0.x, a);
                    a = dot2(v0.y, wq0.y, a);
                    a = dot2(v1.x, wq1.x, a);
                    a = dot2(v1.y, wq1.y, a);
                    a = dot2(v2.x, wq2.x, a);
                    a = dot2(v2.y, wq2.y, a);
                    acc[ii] = a;
                }
            }
        }

        // all-reduce over the 4 quarter-lanes (lanes 4p..4p+3)
#pragma unroll
        for (int k = 0; k < 4; ++k) {
            acc[k] += __shfl_xor(acc[k], 1);
            acc[k] += __shfl_xor(acc[k], 2);
        }
        // lane cq stores h-row cq at w=p
        out[((size_t)dout * 128 + h0 + cq) * 128 + p] = fast_tanh(acc[cq] + bias);

        if (i < 15) __syncthreads();  // drains own DMAs + protects slot reuse
    }
}

extern "C" void kernel_launch(void* const* d_in, const int* in_sizes, int n_in,
                              void* d_out, int out_size, void* d_ws, size_t ws_size,
                              hipStream_t stream) {
    const float* cube = (const float*)d_in[0];
    const float* w1 = (const float*)d_in[1];
    const float* b1 = (const float*)d_in[2];
    const float* w2 = (const float*)d_in[3];
    const float* b2 = (const float*)d_in[4];
    const float* w3 = (const float*)d_in[5];
    const float* b3 = (const float*)d_in[6];
    float* out = (float*)d_out;

    // ws: w2frag@0 (7168B) | w3p@7168 (864B) | w1c@8032 (864B) | x0 @16384 | x1 | x2
    char* ws = (char*)d_ws;
    u16* w2frag = (u16*)ws;
    unsigned* w3p = (unsigned*)(ws + 7168);
    float* w1c = (float*)(ws + 8032);
    u16* x0 = (u16*)(ws + 16384);
    u16* x1 = (u16*)(ws + 16384 + (size_t)PVOX * sizeof(u16));
    u16* x2 = (u16*)(ws + 16384 + (size_t)PVOX * sizeof(u16) + (size_t)PVOX * 8 * sizeof(u16));

    for (int b = 0; b < 2; ++b) {
        if (b == 0) {
            integrate_kernel<<<dim3((PVOX + 255) / 256), dim3(256), 0, stream>>>(
                cube, x0, w1, w2, w3, w2frag, w3p, w1c, x1, x2);
        } else {
            integrate_light_kernel<<<dim3(VOX / 256), dim3(256), 0, stream>>>(
                cube + (size_t)VOX, x0);
        }
        conv1_kernel<<<dim3(VOX / 8 / 256), dim3(256), 0, stream>>>(x0, w1c, b1, x1);
        conv2_mfma_kernel<<<dim3(512), dim3(256), 0, stream>>>(x1, w2frag, b2, x2);
        conv3_kernel<<<dim3(256), dim3(512), 0, stream>>>(
            x2, w3p, b3, out + (size_t)b * VOX);
    }
}

// Round 9
// 228.054 us; speedup vs baseline: 3.7532x; 1.0036x over previous
//
#include <hip/hip_runtime.h>
#include <hip/hip_fp16.h>

#define VOX (128 * 128 * 128)   // 2097152
#define P 130                   // padded dim
#define PP (P * P)              // 16900
#define PVOX (P * P * P)        // 2197000
#define LROW 130
#define PLANE (6 * LROW)        // 780 16B-units per staged dz-plane (conv2)
#define C3PLANE 1560            // 16B-units per staged conv3 plane (6*130 voxels * 32B)

typedef unsigned short u16;
typedef _Float16 f16x2 __attribute__((ext_vector_type(2)));
typedef _Float16 f16x8 __attribute__((ext_vector_type(8)));
typedef __attribute__((ext_vector_type(4))) float f32x4;

__device__ __forceinline__ u16 f2h(float f) {
    return __builtin_bit_cast(unsigned short, (_Float16)f);
}
__device__ __forceinline__ unsigned pkh_relu(float a, float b) {
    float ra = a > 0.f ? a : 0.f, rb = b > 0.f ? b : 0.f;
    return (unsigned)f2h(ra) | ((unsigned)f2h(rb) << 16);
}
__device__ __forceinline__ f16x2 h2(unsigned u) { return __builtin_bit_cast(f16x2, u); }

// dot2: acc += a.x*b.x + a.y*b.y  (f32 accumulate, single V_DOT2_F32_F16)
__device__ __forceinline__ float dot2(unsigned a, unsigned b, float c) {
#if __has_builtin(__builtin_amdgcn_fdot2)
    return __builtin_amdgcn_fdot2(h2(a), h2(b), c, false);
#else
    f16x2 av = h2(a), bv = h2(b);
    c = fmaf((float)av.x, (float)bv.x, c);
    return fmaf((float)av.y, (float)bv.y, c);
#endif
}

// fast tanh: 1 - 2/(1+e^{2x})
__device__ __forceinline__ float fast_tanh(float x) {
    float e = __expf(2.0f * x);
    return 1.0f - 2.0f * __builtin_amdgcn_rcpf(1.0f + e);
}

// async global->LDS DMA, 16B per lane. LDS dest = wave-uniform base + lane*16.
__device__ __forceinline__ void gload_lds16(const u16* g, u16* l) {
    __builtin_amdgcn_global_load_lds(
        (const __attribute__((address_space(1))) unsigned int*)g,
        (__attribute__((address_space(3))) unsigned int*)l,
        16, 0, 0);
}

// counted vmcnt wait: lets the newest prefetch DMAs stay in flight across the
// barrier (the __syncthreads vmcnt(0) drain was the ring's structural stall).
#define WAITCNT(N) asm volatile("s_waitcnt vmcnt(" #N ")" ::: "memory")

// heavy integrate (batch 0 only): x0 full (incl halo), weight prep, halo zeroing.
//  x0 padded f16 [130^3] = cube * (1 + 0.1*sin(2pi*(d+h+w)/384)), halo = 0
//  zero halo shells of x1 (8ch) / x2 (16ch)
//  w2frag[(s*64+lane)*8+j] = f16(w2[oc=lane&15][ic=j][tap=s*4+(lane>>4)]), 0 if tap>26
//  w3p[tap*8+j] = packed f16 pair (w3[2j][tap], w3[2j+1][tap])
//  w1c[tap*8+c] = f32 w1[c][tap]   (channel-contiguous for conv1 scalar FMA)
__global__ __launch_bounds__(256) void integrate_kernel(
    const float* __restrict__ in, u16* __restrict__ x0,
    const float* __restrict__ w1, const float* __restrict__ w2,
    const float* __restrict__ w3, u16* __restrict__ w2frag,
    unsigned* __restrict__ w3p, float* __restrict__ w1c,
    u16* __restrict__ x1, u16* __restrict__ x2) {
    int i = blockIdx.x * 256 + threadIdx.x;
    if (i < 3584) {
        int j = i & 7, l = (i >> 3) & 63, s = i >> 9;
        int tap = s * 4 + (l >> 4), oc = l & 15;
        float v = (tap < 27) ? w2[(oc * 8 + j) * 27 + tap] : 0.0f;
        w2frag[i] = f2h(v);
    }
    if (i < 216) {
        int tap = i >> 3, j = i & 7;
        w3p[i] = (unsigned)f2h(w3[(2 * j) * 27 + tap]) |
                 ((unsigned)f2h(w3[(2 * j + 1) * 27 + tap]) << 16);
        // w1c: tap-major, 8 channels contiguous
        int c = i & 7;
        w1c[i] = w1[c * 27 + tap];
    }
    if (i >= PVOX) return;
    int d = i / PP;
    int r = i - d * PP;
    int h = r / P;
    int w = r - h * P;
    const bool interior = (d >= 1 && d <= 128 && h >= 1 && h <= 128 && w >= 1 && w <= 128);
    float v = 0.0f;
    if (interior) {
        int s = (d - 1) + (h - 1) + (w - 1);
        float fld = 1.0f + 0.1f * __sinf(6.283185307179586f * (float)s / 384.0f);
        v = in[(size_t)(d - 1) * 16384 + (h - 1) * 128 + (w - 1)] * fld;
    } else {
        uint4 z = {0u, 0u, 0u, 0u};
        *(uint4*)(x1 + (size_t)i * 8) = z;
        *(uint4*)(x2 + (size_t)i * 16) = z;
        *(uint4*)(x2 + (size_t)i * 16 + 8) = z;
    }
    x0[i] = f2h(v);
}

// light integrate (batch 1): x0 interior only (halo already zero; prep idempotent)
__global__ __launch_bounds__(256) void integrate_light_kernel(
    const float* __restrict__ in, u16* __restrict__ x0) {
    const int i = blockIdx.x * 256 + threadIdx.x;  // VOX threads exactly
    const int d = i >> 14, h = (i >> 7) & 127, w = i & 127;
    const int s = d + h + w;
    const float fld = 1.0f + 0.1f * __sinf((float)s * 0.016362461737446838f);
    x0[(size_t)(d + 1) * PP + (h + 1) * P + (w + 1)] = f2h(in[i] * fld);
}

// conv1: x0 padded f16 [130^3] -> x1 f16 channels-last padded [130^3][8], relu.
// Strip 4(h) x 2(w) voxels/thread. SCALAR-FMA form: acc as 64 flat floats,
// weights via wave-uniform constant-offset loads (SGPR-resident s_load),
// acts as 4 scalar floats -> each FMA is one v_fmac_f32 (sgpr, vgpr).
__global__ __launch_bounds__(256) void conv1_kernel(
    const u16* __restrict__ x0, const float* __restrict__ w1c,
    const float* __restrict__ b1, u16* __restrict__ x1) {
    const int t = blockIdx.x * 256 + threadIdx.x;  // VOX/8 threads
    const int w0 = (t & 63) * 2;
    const int h0 = ((t >> 6) & 31) * 4;
    const int d = t >> 11;

    float acc[4][2][8];  // [i(h)][m(w)][c]
#pragma unroll
    for (int c = 0; c < 8; ++c) {
        const float b = b1[c];
#pragma unroll
        for (int i = 0; i < 4; ++i) { acc[i][0][c] = b; acc[i][1][c] = b; }
    }

#pragma unroll
    for (int dz = 0; dz < 3; ++dz) {
        const u16* zb = x0 + (size_t)(d + dz) * PP + (size_t)h0 * P + w0;
        const float* wz = w1c + dz * 9 * 8;  // 72 floats, uniform const offsets
#pragma unroll
        for (int r = 0; r < 6; ++r) {
            const u16* rp = zb + r * P;
            const unsigned u0 = *(const unsigned*)rp;
            const unsigned u1 = *(const unsigned*)(rp + 2);
            float vv[4];
            vv[0] = (float)h2(u0).x; vv[1] = (float)h2(u0).y;
            vv[2] = (float)h2(u1).x; vv[3] = (float)h2(u1).y;
#pragma unroll
            for (int dy = 0; dy < 3; ++dy) {
                const int i = r - dy;
                if (i < 0 || i > 3) continue;  // resolved at compile time
#pragma unroll
                for (int dx = 0; dx < 3; ++dx) {
                    const float a0 = vv[dx];
                    const float a1 = vv[dx + 1];
                    const float* wp = wz + (dy * 3 + dx) * 8;
#pragma unroll
                    for (int c = 0; c < 8; ++c) {
                        const float wt = wp[c];
                        acc[i][0][c] = fmaf(wt, a0, acc[i][0][c]);
                        acc[i][1][c] = fmaf(wt, a1, acc[i][1][c]);
                    }
                }
            }
        }
    }
    const size_t e0 = ((size_t)(d + 1) * P + (h0 + 1)) * P + (w0 + 1);
#pragma unroll
    for (int i = 0; i < 4; ++i) {
        uint4 oA, oB;
        oA.x = pkh_relu(acc[i][0][0], acc[i][0][1]);
        oA.y = pkh_relu(acc[i][0][2], acc[i][0][3]);
        oA.z = pkh_relu(acc[i][0][4], acc[i][0][5]);
        oA.w = pkh_relu(acc[i][0][6], acc[i][0][7]);
        oB.x = pkh_relu(acc[i][1][0], acc[i][1][1]);
        oB.y = pkh_relu(acc[i][1][2], acc[i][1][3]);
        oB.z = pkh_relu(acc[i][1][4], acc[i][1][5]);
        oB.w = pkh_relu(acc[i][1][6], acc[i][1][7]);
        *(uint4*)(x1 + (e0 + (size_t)i * P) * 8) = oA;
        *(uint4*)(x1 + (e0 + (size_t)i * P + 1) * 8) = oB;
    }
}

// conv2: rolling-d LDS-staged implicit-GEMM MFMA, async DMA staging.
// d-chunk = 8 -> grid 512 blocks = 2/CU, ALL resident.
// COUNTED-VMCNT ring (T3/T4): stage(i+3) -> vmcnt(N) -> s_barrier ->
// compute(i) -> s_barrier. N=19 steady (16 stores + 3 DMAs after the target
// plane's DMAs, in-order vmcnt queue) keeps the fresh prefetch in flight;
// the old __syncthreads drained vmcnt(0) every step.
__global__ __launch_bounds__(256) void conv2_mfma_kernel(
    const u16* __restrict__ x1, const u16* __restrict__ w2frag,
    const float* __restrict__ b2, u16* __restrict__ x2) {
    __shared__ u16 sm[4 * PLANE * 8];  // 49920 B

    const int tid = threadIdx.x;
    const int lane = tid & 63;
    const int wv = tid >> 6;  // output h-row offset 0..3
    const int q = lane >> 4;
    const int mi = lane & 15;
    const int D0 = (blockIdx.x >> 5) * 8;   // d-chunk base (unpadded out d)
    const int h0 = (blockIdx.x & 31) * 4;   // h-tile base

    // weight A-frags (7KB table, L1-resident)
    f16x8 wf[7];
#pragma unroll
    for (int s = 0; s < 7; ++s)
        wf[s] = *(const f16x8*)(w2frag + (size_t)(s * 64 + lane) * 8);

    // async stage planes D0..D0+2 (padded plane index pd covers rows h0..h0+5)
#pragma unroll
    for (int p = 0; p < 3; ++p) {
        const int pd = D0 + p;
        const int slot = pd & 3;
        const u16* gb = x1 + ((size_t)(pd * P + h0) * P) * 8;
        u16* lb = sm + (size_t)slot * PLANE * 8;
#pragma unroll
        for (int k = 0; k < 3; ++k) {
            const int u0 = wv * 64 + k * 256;
            gload_lds16(gb + (size_t)(u0 + lane) * 8, lb + (size_t)u0 * 8);
        }
        if (wv == 0 && lane < PLANE - 768)
            gload_lds16(gb + (size_t)(768 + lane) * 8, lb + (size_t)768 * 8);
    }
    WAITCNT(0);
    __builtin_amdgcn_s_barrier();

    const float4 bv = *(const float4*)(b2 + q * 4);

#pragma unroll 1
    for (int i = 0; i < 8; ++i) {
        const int dout = D0 + i;

        // async prefetch plane dout+3 into its ring slot (unread this step)
        if (i < 7) {
            const int pd = dout + 3;
            const int slot = pd & 3;
            const u16* gb = x1 + ((size_t)(pd * P + h0) * P) * 8;
            u16* lb = sm + (size_t)slot * PLANE * 8;
#pragma unroll
            for (int k = 0; k < 3; ++k) {
                const int u0 = wv * 64 + k * 256;
                gload_lds16(gb + (size_t)(u0 + lane) * 8, lb + (size_t)u0 * 8);
            }
            if (wv == 0 && lane < PLANE - 768)
                gload_lds16(gb + (size_t)(768 + lane) * 8, lb + (size_t)768 * 8);
        }

        // wait: target = plane dout+2's DMAs (issued last step). Queue after
        // target: stores(i-1)[16] + DMA(i+3)[3] -> N=19 steady; i=0: only own
        // fresh DMAs [3] outstanding (prologue drained); i=7: stores only.
        if (i == 0)     WAITCNT(3);
        else if (i < 7) WAITCNT(19);
        else            WAITCNT(16);
        __builtin_amdgcn_s_barrier();

        // compute output plane dout from slots (dout..dout+2)&3
        f32x4 acc[8];
#pragma unroll
        for (int t = 0; t < 8; ++t) acc[t] = (f32x4){0.f, 0.f, 0.f, 0.f};

#pragma unroll
        for (int s = 0; s < 7; ++s) {
            int tap = s * 4 + q;
            if (tap > 26) tap = 26;  // pad tap: weight frag is zero there
            const int dz = tap / 9;
            const int rem = tap - dz * 9;
            const int dy = rem / 3;
            const int dx = rem - dy * 3;
            const int slot = (dout + dz) & 3;
            const u16* bp = sm + ((size_t)(slot * 6 + wv + dy) * LROW + (mi + dx)) * 8;
#pragma unroll
            for (int t = 0; t < 8; ++t) {
                f16x8 act = *(const f16x8*)(bp + t * 128);  // +16 voxels
                acc[t] = __builtin_amdgcn_mfma_f32_16x16x32_f16(wf[s], act, acc[t], 0, 0, 0);
            }
        }

        // D: row(oc)=q*4+r, col(voxel)=mi -> lane stores 4 consecutive channels
        const size_t obase = ((size_t)(dout + 1) * P + (h0 + wv + 1)) * P + 1;
#pragma unroll
        for (int t = 0; t < 8; ++t) {
            uint2 o;
            o.x = pkh_relu(acc[t][0] + bv.x, acc[t][1] + bv.y);
            o.y = pkh_relu(acc[t][2] + bv.z, acc[t][3] + bv.w);
            *(uint2*)(x2 + (obase + 16 * t + mi) * 16 + q * 4) = o;
        }

        // protect slot (dout)&3 from next step's DMA overwrite
        if (i < 7) __builtin_amdgcn_s_barrier();
    }
}

// conv3: LDS-ring staged, 512 threads/block, d-chunk 16, grid 256 = 1/CU in
// one round. Thread = (w-column p=tid>>2, channel quarter cq=tid&3); 8B LDS
// reads, conflict-free; 4-lane shfl_xor all-reduce. COUNTED-VMCNT ring:
// same T3/T4 structure as conv2 -- at 1 block/CU the __syncthreads vmcnt(0)
// drain was ~1.7us/step of pure idle (R8: 2.4us/step vs 0.72us LDS floor).
__global__ __launch_bounds__(512, 1) void conv3_kernel(
    const u16* __restrict__ x2, const unsigned* __restrict__ w3p,
    const float* __restrict__ b3, float* __restrict__ out) {
    __shared__ u16 sm[4 * C3PLANE * 8];  // 99840 B

    const int tid = threadIdx.x;
    const int lane = tid & 63;
    const int wv = tid >> 6;               // 0..7
    const int cq = tid & 3;                // channel quarter (ch 4cq..4cq+3)
    const int p = tid >> 2;                // w coordinate 0..127
    const int D0 = (blockIdx.x >> 5) * 16; // d-chunk base (unpadded out d)
    const int h0 = (blockIdx.x & 31) * 4;  // h-tile base

    // preload 27 taps x this quarter's 2 packed ch-pair words
    uint2 wt[27];
#pragma unroll
    for (int q = 0; q < 27; ++q)
        wt[q] = *(const uint2*)(w3p + q * 8 + cq * 2);

    // stage planes D0..D0+2 (plane = padded rows h0..h0+5 x 130 vox x 32B,
    // globally contiguous; 1560 16B-units = 3 x 512 lanes + 24 remainder)
#pragma unroll
    for (int pp = 0; pp < 3; ++pp) {
        const int pd = D0 + pp;
        const int slot = pd & 3;
        const u16* gb = x2 + ((size_t)(pd * P + h0) * P) * 16;
        u16* lb = sm + (size_t)slot * C3PLANE * 8;
#pragma unroll
        for (int k = 0; k < 3; ++k) {
            const int u0 = wv * 64 + k * 512;
            gload_lds16(gb + (size_t)(u0 + lane) * 8, lb + (size_t)u0 * 8);
        }
        if (wv == 0 && lane < C3PLANE - 1536)
            gload_lds16(gb + (size_t)(1536 + lane) * 8, lb + (size_t)1536 * 8);
    }
    WAITCNT(0);
    __builtin_amdgcn_s_barrier();

    const float bias = b3[0];

#pragma unroll 1
    for (int i = 0; i < 16; ++i) {
        const int dout = D0 + i;

        // async prefetch plane dout+3 into its ring slot (unread this step)
        if (i < 15) {
            const int pd = dout + 3;
            const int slot = pd & 3;
            const u16* gb = x2 + ((size_t)(pd * P + h0) * P) * 16;
            u16* lb = sm + (size_t)slot * C3PLANE * 8;
#pragma unroll
            for (int k = 0; k < 3; ++k) {
                const int u0 = wv * 64 + k * 512;
                gload_lds16(gb + (size_t)(u0 + lane) * 8, lb + (size_t)u0 * 8);
            }
            if (wv == 0 && lane < C3PLANE - 1536)
                gload_lds16(gb + (size_t)(1536 + lane) * 8, lb + (size_t)1536 * 8);
        }

        // wait: target = plane dout+2's DMAs. After target in the in-order
        // vmcnt queue: store(i-1)[1] + DMA(i+3)[3] -> N=4 steady.
        if (i == 0)      WAITCNT(3);
        else if (i < 15) WAITCNT(4);
        else             WAITCNT(1);
        __builtin_amdgcn_s_barrier();

        float acc[4] = {0.f, 0.f, 0.f, 0.f};  // h-rows 0..3, this quarter's sum
#pragma unroll
        for (int dz = 0; dz < 3; ++dz) {       // fully unrolled: wt[] static idx
            const int slot = (dout + dz) & 3;
            const u16* sp = sm + (size_t)slot * C3PLANE * 8 + (size_t)cq * 4;
#pragma unroll
            for (int r = 0; r < 6; ++r) {
                const u16* rp = sp + (size_t)(r * 130 + p) * 16;
                const uint2 v0 = *(const uint2*)(rp);
                const uint2 v1 = *(const uint2*)(rp + 16);
                const uint2 v2 = *(const uint2*)(rp + 32);
#pragma unroll
                for (int dy = 0; dy < 3; ++dy) {
                    const int ii = r - dy;
                    if (ii < 0 || ii > 3) continue;  // compile-time
                    const uint2 wq0 = wt[dz * 9 + dy * 3 + 0];
                    const uint2 wq1 = wt[dz * 9 + dy * 3 + 1];
                    const uint2 wq2 = wt[dz * 9 + dy * 3 + 2];
                    float a = acc[ii];
                    a = dot2(v0.x, wq0.x, a);
                    a = dot2(v0.y, wq0.y, a);
                    a = dot2(v1.x, wq1.x, a);
                    a = dot2(v1.y, wq1.y, a);
                    a = dot2(v2.x, wq2.x, a);
                    a = dot2(v2.y, wq2.y, a);
                    acc[ii] = a;
                }
            }
        }

        // all-reduce over the 4 quarter-lanes (lanes 4p..4p+3)
#pragma unroll
        for (int k = 0; k < 4; ++k) {
            acc[k] += __shfl_xor(acc[k], 1);
            acc[k] += __shfl_xor(acc[k], 2);
        }
        // lane cq stores h-row cq at w=p
        out[((size_t)dout * 128 + h0 + cq) * 128 + p] = fast_tanh(acc[cq] + bias);

        // protect slot (dout)&3 from next step's DMA overwrite
        if (i < 15) __builtin_amdgcn_s_barrier();
    }
}

extern "C" void kernel_launch(void* const* d_in, const int* in_sizes, int n_in,
                              void* d_out, int out_size, void* d_ws, size_t ws_size,
                              hipStream_t stream) {
    const float* cube = (const float*)d_in[0];
    const float* w1 = (const float*)d_in[1];
    const float* b1 = (const float*)d_in[2];
    const float* w2 = (const float*)d_in[3];
    const float* b2 = (const float*)d_in[4];
    const float* w3 = (const float*)d_in[5];
    const float* b3 = (const float*)d_in[6];
    float* out = (float*)d_out;

    // ws: w2frag@0 (7168B) | w3p@7168 (864B) | w1c@8032 (864B) | x0 @16384 | x1 | x2
    char* ws = (char*)d_ws;
    u16* w2frag = (u16*)ws;
    unsigned* w3p = (unsigned*)(ws + 7168);
    float* w1c = (float*)(ws + 8032);
    u16* x0 = (u16*)(ws + 16384);
    u16* x1 = (u16*)(ws + 16384 + (size_t)PVOX * sizeof(u16));
    u16* x2 = (u16*)(ws + 16384 + (size_t)PVOX * sizeof(u16) + (size_t)PVOX * 8 * sizeof(u16));

    for (int b = 0; b < 2; ++b) {
        if (b == 0) {
            integrate_kernel<<<dim3((PVOX + 255) / 256), dim3(256), 0, stream>>>(
                cube, x0, w1, w2, w3, w2frag, w3p, w1c, x1, x2);
        } else {
            integrate_light_kernel<<<dim3(VOX / 256), dim3(256), 0, stream>>>(
                cube + (size_t)VOX, x0);
        }
        conv1_kernel<<<dim3(VOX / 8 / 256), dim3(256), 0, stream>>>(x0, w1c, b1, x1);
        conv2_mfma_kernel<<<dim3(512), dim3(256), 0, stream>>>(x1, w2frag, b2, x2);
        conv3_kernel<<<dim3(256), dim3(512), 0, stream>>>(
            x2, w3p, b3, out + (size_t)b * VOX);
    }
}

// Round 10
// 220.867 us; speedup vs baseline: 3.8753x; 1.0325x over previous
//
#include <hip/hip_runtime.h>
#include <hip/hip_fp16.h>

#define VOX (128 * 128 * 128)   // 2097152
#define P 130                   // padded dim
#define PP (P * P)              // 16900
#define PVOX (P * P * P)        // 2197000
#define LROW 130
#define PLANE (6 * LROW)        // 780 16B-units per staged dz-plane (conv2)

typedef unsigned short u16;
typedef _Float16 f16x2 __attribute__((ext_vector_type(2)));
typedef _Float16 f16x8 __attribute__((ext_vector_type(8)));
typedef __attribute__((ext_vector_type(4))) float f32x4;

__device__ __forceinline__ u16 f2h(float f) {
    return __builtin_bit_cast(unsigned short, (_Float16)f);
}
__device__ __forceinline__ unsigned pkh_relu(float a, float b) {
    float ra = a > 0.f ? a : 0.f, rb = b > 0.f ? b : 0.f;
    return (unsigned)f2h(ra) | ((unsigned)f2h(rb) << 16);
}
__device__ __forceinline__ f16x2 h2(unsigned u) { return __builtin_bit_cast(f16x2, u); }

// dot2: acc += a.x*b.x + a.y*b.y  (f32 accumulate, single V_DOT2_F32_F16)
__device__ __forceinline__ float dot2(unsigned a, unsigned b, float c) {
#if __has_builtin(__builtin_amdgcn_fdot2)
    return __builtin_amdgcn_fdot2(h2(a), h2(b), c, false);
#else
    f16x2 av = h2(a), bv = h2(b);
    c = fmaf((float)av.x, (float)bv.x, c);
    return fmaf((float)av.y, (float)bv.y, c);
#endif
}

// fast tanh: 1 - 2/(1+e^{2x})
__device__ __forceinline__ float fast_tanh(float x) {
    float e = __expf(2.0f * x);
    return 1.0f - 2.0f * __builtin_amdgcn_rcpf(1.0f + e);
}

// async global->LDS DMA, 16B per lane. LDS dest = wave-uniform base + lane*16.
__device__ __forceinline__ void gload_lds16(const u16* g, u16* l) {
    __builtin_amdgcn_global_load_lds(
        (const __attribute__((address_space(1))) unsigned int*)g,
        (__attribute__((address_space(3))) unsigned int*)l,
        16, 0, 0);
}

// counted vmcnt wait (conv2 ring): keeps fresh prefetch DMAs in flight
// across the barrier instead of the __syncthreads vmcnt(0) drain.
#define WAITCNT(N) asm volatile("s_waitcnt vmcnt(" #N ")" ::: "memory")

// heavy integrate (batch 0 only): x0 full (incl halo), weight prep, halo zeroing.
//  x0 padded f16 [130^3] = cube * (1 + 0.1*sin(2pi*(d+h+w)/384)), halo = 0
//  zero halo shells of x1 (8ch) / x2 (16ch)
//  w2frag[(s*64+lane)*8+j] = f16(w2[oc=lane&15][ic=j][tap=s*4+(lane>>4)]), 0 if tap>26
//  w3p[tap*8+j] = packed f16 pair (w3[2j][tap], w3[2j+1][tap])
//  w1c[tap*8+c] = f32 w1[c][tap]   (channel-contiguous for conv1 scalar FMA)
__global__ __launch_bounds__(256) void integrate_kernel(
    const float* __restrict__ in, u16* __restrict__ x0,
    const float* __restrict__ w1, const float* __restrict__ w2,
    const float* __restrict__ w3, u16* __restrict__ w2frag,
    unsigned* __restrict__ w3p, float* __restrict__ w1c,
    u16* __restrict__ x1, u16* __restrict__ x2) {
    int i = blockIdx.x * 256 + threadIdx.x;
    if (i < 3584) {
        int j = i & 7, l = (i >> 3) & 63, s = i >> 9;
        int tap = s * 4 + (l >> 4), oc = l & 15;
        float v = (tap < 27) ? w2[(oc * 8 + j) * 27 + tap] : 0.0f;
        w2frag[i] = f2h(v);
    }
    if (i < 216) {
        int tap = i >> 3, j = i & 7;
        w3p[i] = (unsigned)f2h(w3[(2 * j) * 27 + tap]) |
                 ((unsigned)f2h(w3[(2 * j + 1) * 27 + tap]) << 16);
        // w1c: tap-major, 8 channels contiguous
        int c = i & 7;
        w1c[i] = w1[c * 27 + tap];
    }
    if (i >= PVOX) return;
    int d = i / PP;
    int r = i - d * PP;
    int h = r / P;
    int w = r - h * P;
    const bool interior = (d >= 1 && d <= 128 && h >= 1 && h <= 128 && w >= 1 && w <= 128);
    float v = 0.0f;
    if (interior) {
        int s = (d - 1) + (h - 1) + (w - 1);
        float fld = 1.0f + 0.1f * __sinf(6.283185307179586f * (float)s / 384.0f);
        v = in[(size_t)(d - 1) * 16384 + (h - 1) * 128 + (w - 1)] * fld;
    } else {
        uint4 z = {0u, 0u, 0u, 0u};
        *(uint4*)(x1 + (size_t)i * 8) = z;
        *(uint4*)(x2 + (size_t)i * 16) = z;
        *(uint4*)(x2 + (size_t)i * 16 + 8) = z;
    }
    x0[i] = f2h(v);
}

// conv1: x0 padded f16 [130^3] -> x1 f16 channels-last padded [130^3][8], relu.
// Strip 4(h) x 2(w) voxels/thread. SCALAR-FMA form: acc as 64 flat floats,
// weights via wave-uniform constant-offset loads (SGPR-resident s_load),
// acts as 4 scalar floats -> each FMA is one v_fmac_f32 (sgpr, vgpr).
__global__ __launch_bounds__(256) void conv1_kernel(
    const u16* __restrict__ x0, const float* __restrict__ w1c,
    const float* __restrict__ b1, u16* __restrict__ x1) {
    const int t = blockIdx.x * 256 + threadIdx.x;  // VOX/8 threads
    const int w0 = (t & 63) * 2;
    const int h0 = ((t >> 6) & 31) * 4;
    const int d = t >> 11;

    float acc[4][2][8];  // [i(h)][m(w)][c]
#pragma unroll
    for (int c = 0; c < 8; ++c) {
        const float b = b1[c];
#pragma unroll
        for (int i = 0; i < 4; ++i) { acc[i][0][c] = b; acc[i][1][c] = b; }
    }

#pragma unroll
    for (int dz = 0; dz < 3; ++dz) {
        const u16* zb = x0 + (size_t)(d + dz) * PP + (size_t)h0 * P + w0;
        const float* wz = w1c + dz * 9 * 8;  // 72 floats, uniform const offsets
#pragma unroll
        for (int r = 0; r < 6; ++r) {
            const u16* rp = zb + r * P;
            const unsigned u0 = *(const unsigned*)rp;
            const unsigned u1 = *(const unsigned*)(rp + 2);
            float vv[4];
            vv[0] = (float)h2(u0).x; vv[1] = (float)h2(u0).y;
            vv[2] = (float)h2(u1).x; vv[3] = (float)h2(u1).y;
#pragma unroll
            for (int dy = 0; dy < 3; ++dy) {
                const int i = r - dy;
                if (i < 0 || i > 3) continue;  // resolved at compile time
#pragma unroll
                for (int dx = 0; dx < 3; ++dx) {
                    const float a0 = vv[dx];
                    const float a1 = vv[dx + 1];
                    const float* wp = wz + (dy * 3 + dx) * 8;
#pragma unroll
                    for (int c = 0; c < 8; ++c) {
                        const float wt = wp[c];
                        acc[i][0][c] = fmaf(wt, a0, acc[i][0][c]);
                        acc[i][1][c] = fmaf(wt, a1, acc[i][1][c]);
                    }
                }
            }
        }
    }
    const size_t e0 = ((size_t)(d + 1) * P + (h0 + 1)) * P + (w0 + 1);
#pragma unroll
    for (int i = 0; i < 4; ++i) {
        uint4 oA, oB;
        oA.x = pkh_relu(acc[i][0][0], acc[i][0][1]);
        oA.y = pkh_relu(acc[i][0][2], acc[i][0][3]);
        oA.z = pkh_relu(acc[i][0][4], acc[i][0][5]);
        oA.w = pkh_relu(acc[i][0][6], acc[i][0][7]);
        oB.x = pkh_relu(acc[i][1][0], acc[i][1][1]);
        oB.y = pkh_relu(acc[i][1][2], acc[i][1][3]);
        oB.z = pkh_relu(acc[i][1][4], acc[i][1][5]);
        oB.w = pkh_relu(acc[i][1][6], acc[i][1][7]);
        *(uint4*)(x1 + (e0 + (size_t)i * P) * 8) = oA;
        *(uint4*)(x1 + (e0 + (size_t)i * P + 1) * 8) = oB;
    }
}

// conv2: rolling-d LDS-staged implicit-GEMM MFMA, async DMA staging.
// d-chunk = 8 -> grid 512 blocks = 2/CU, ALL resident.
// COUNTED-VMCNT ring (T3/T4): stage(i+3) -> vmcnt(N) -> s_barrier ->
// compute(i) -> s_barrier. N=19 steady keeps the fresh prefetch in flight.
__global__ __launch_bounds__(256) void conv2_mfma_kernel(
    const u16* __restrict__ x1, const u16* __restrict__ w2frag,
    const float* __restrict__ b2, u16* __restrict__ x2) {
    __shared__ u16 sm[4 * PLANE * 8];  // 49920 B

    const int tid = threadIdx.x;
    const int lane = tid & 63;
    const int wv = tid >> 6;  // output h-row offset 0..3
    const int q = lane >> 4;
    const int mi = lane & 15;
    const int D0 = (blockIdx.x >> 5) * 8;   // d-chunk base (unpadded out d)
    const int h0 = (blockIdx.x & 31) * 4;   // h-tile base

    // weight A-frags (7KB table, L1-resident)
    f16x8 wf[7];
#pragma unroll
    for (int s = 0; s < 7; ++s)
        wf[s] = *(const f16x8*)(w2frag + (size_t)(s * 64 + lane) * 8);

    // async stage planes D0..D0+2 (padded plane index pd covers rows h0..h0+5)
#pragma unroll
    for (int p = 0; p < 3; ++p) {
        const int pd = D0 + p;
        const int slot = pd & 3;
        const u16* gb = x1 + ((size_t)(pd * P + h0) * P) * 8;
        u16* lb = sm + (size_t)slot * PLANE * 8;
#pragma unroll
        for (int k = 0; k < 3; ++k) {
            const int u0 = wv * 64 + k * 256;
            gload_lds16(gb + (size_t)(u0 + lane) * 8, lb + (size_t)u0 * 8);
        }
        if (wv == 0 && lane < PLANE - 768)
            gload_lds16(gb + (size_t)(768 + lane) * 8, lb + (size_t)768 * 8);
    }
    WAITCNT(0);
    __builtin_amdgcn_s_barrier();

    const float4 bv = *(const float4*)(b2 + q * 4);

#pragma unroll 1
    for (int i = 0; i < 8; ++i) {
        const int dout = D0 + i;

        // async prefetch plane dout+3 into its ring slot (unread this step)
        if (i < 7) {
            const int pd = dout + 3;
            const int slot = pd & 3;
            const u16* gb = x1 + ((size_t)(pd * P + h0) * P) * 8;
            u16* lb = sm + (size_t)slot * PLANE * 8;
#pragma unroll
            for (int k = 0; k < 3; ++k) {
                const int u0 = wv * 64 + k * 256;
                gload_lds16(gb + (size_t)(u0 + lane) * 8, lb + (size_t)u0 * 8);
            }
            if (wv == 0 && lane < PLANE - 768)
                gload_lds16(gb + (size_t)(768 + lane) * 8, lb + (size_t)768 * 8);
        }

        // wait: target = plane dout+2's DMAs (issued last step). Queue after
        // target: stores(i-1)[16] + DMA(i+3)[3] -> N=19 steady; i=0: only own
        // fresh DMAs [3] outstanding (prologue drained); i=7: stores only.
        if (i == 0)     WAITCNT(3);
        else if (i < 7) WAITCNT(19);
        else            WAITCNT(16);
        __builtin_amdgcn_s_barrier();

        // compute output plane dout from slots (dout..dout+2)&3
        f32x4 acc[8];
#pragma unroll
        for (int t = 0; t < 8; ++t) acc[t] = (f32x4){0.f, 0.f, 0.f, 0.f};

#pragma unroll
        for (int s = 0; s < 7; ++s) {
            int tap = s * 4 + q;
            if (tap > 26) tap = 26;  // pad tap: weight frag is zero there
            const int dz = tap / 9;
            const int rem = tap - dz * 9;
            const int dy = rem / 3;
            const int dx = rem - dy * 3;
            const int slot = (dout + dz) & 3;
            const u16* bp = sm + ((size_t)(slot * 6 + wv + dy) * LROW + (mi + dx)) * 8;
#pragma unroll
            for (int t = 0; t < 8; ++t) {
                f16x8 act = *(const f16x8*)(bp + t * 128);  // +16 voxels
                acc[t] = __builtin_amdgcn_mfma_f32_16x16x32_f16(wf[s], act, acc[t], 0, 0, 0);
            }
        }

        // D: row(oc)=q*4+r, col(voxel)=mi -> lane stores 4 consecutive channels
        const size_t obase = ((size_t)(dout + 1) * P + (h0 + wv + 1)) * P + 1;
#pragma unroll
        for (int t = 0; t < 8; ++t) {
            uint2 o;
            o.x = pkh_relu(acc[t][0] + bv.x, acc[t][1] + bv.y);
            o.y = pkh_relu(acc[t][2] + bv.z, acc[t][3] + bv.w);
            *(uint2*)(x2 + (obase + 16 * t + mi) * 16 + q * 4) = o;
        }

        // protect slot (dout)&3 from next step's DMA overwrite
        if (i < 7) __builtin_amdgcn_s_barrier();
    }
}

// conv3: naive register form (R2 structure — the best measured), but strip
// 2(d) x 2(h) x 1(w) -> VOX/4 threads, 2048 blocks = 8 blocks/CU, 8 waves/
// SIMD at VGPR~40: HALF the serial (z,r) chain per thread and DOUBLE the
// latency-hiding TLP vs R2's 4 waves/SIMD (cross-round evidence: conv3 is
// latency-bound and responds only to wave count). Issued bytes 384 B/voxel.
// FAT-KERNEL: blocks >= 2048 run integrate_light for batch 1 (independent
// work: x0 was last read by conv1(b0)) -- hides ~3.5us + one launch gap.
__global__ __launch_bounds__(256) void conv3_kernel(
    const u16* __restrict__ x2, const unsigned* __restrict__ w3p,
    const float* __restrict__ b3, float* __restrict__ out,
    const float* __restrict__ in_b1, u16* __restrict__ x0) {
    const int bid = blockIdx.x;
    if (bid >= 2048) {
        // integrate_light(batch 1): x0 interior only (halo already zero)
        const int i = (bid - 2048) * 256 + threadIdx.x;  // VOX threads
        const int d = i >> 14, h = (i >> 7) & 127, w = i & 127;
        const float fld =
            1.0f + 0.1f * __sinf((float)(d + h + w) * 0.016362461737446838f);
        x0[(size_t)(d + 1) * PP + (h + 1) * P + (w + 1)] = f2h(in_b1[i] * fld);
        return;
    }
    const int t = bid * 256 + threadIdx.x;  // VOX/4 threads
    const int w = t & 127;
    const int h0 = ((t >> 7) & 63) * 2;
    const int d0 = (t >> 13) * 2;

    float accA[2][2], accB[2][2];  // [dd][i(h)]
#pragma unroll
    for (int dd = 0; dd < 2; ++dd)
#pragma unroll
        for (int i = 0; i < 2; ++i) { accA[dd][i] = 0.f; accB[dd][i] = 0.f; }

#pragma unroll 1
    for (int z = 0; z < 4; ++z) {  // padded z-plane = d0 + z
        const u16* zb = x2 + ((size_t)((d0 + z) * P + h0) * P + w) * 16;
#pragma unroll
        for (int r = 0; r < 4; ++r) {  // padded row = h0 + r
            const u16* rp = zb + (size_t)r * (P * 16);
            const uint4 c0l = *(const uint4*)(rp);
            const uint4 c0h = *(const uint4*)(rp + 8);
            const uint4 c1l = *(const uint4*)(rp + 16);
            const uint4 c1h = *(const uint4*)(rp + 24);
            const uint4 c2l = *(const uint4*)(rp + 32);
            const uint4 c2h = *(const uint4*)(rp + 40);
#pragma unroll
            for (int dd = 0; dd < 2; ++dd) {
                const int dz = z - dd;
                if (dz < 0 || dz > 2) continue;  // wave-uniform runtime guard
                const unsigned* wz = w3p + dz * 9 * 8;
#pragma unroll
                for (int dy = 0; dy < 3; ++dy) {
                    const int i = r - dy;
                    if (i < 0 || i > 1) continue;  // compile-time after unroll
                    const unsigned* wp = wz + dy * 3 * 8;
                    float a = accA[dd][i], b = accB[dd][i];
                    a = dot2(c0l.x, wp[0], a);  b = dot2(c0l.y, wp[1], b);
                    a = dot2(c0l.z, wp[2], a);  b = dot2(c0l.w, wp[3], b);
                    a = dot2(c0h.x, wp[4], a);  b = dot2(c0h.y, wp[5], b);
                    a = dot2(c0h.z, wp[6], a);  b = dot2(c0h.w, wp[7], b);
                    a = dot2(c1l.x, wp[8], a);  b = dot2(c1l.y, wp[9], b);
                    a = dot2(c1l.z, wp[10], a); b = dot2(c1l.w, wp[11], b);
                    a = dot2(c1h.x, wp[12], a); b = dot2(c1h.y, wp[13], b);
                    a = dot2(c1h.z, wp[14], a); b = dot2(c1h.w, wp[15], b);
                    a = dot2(c2l.x, wp[16], a); b = dot2(c2l.y, wp[17], b);
                    a = dot2(c2l.z, wp[18], a); b = dot2(c2l.w, wp[19], b);
                    a = dot2(c2h.x, wp[20], a); b = dot2(c2h.y, wp[21], b);
                    a = dot2(c2h.z, wp[22], a); b = dot2(c2h.w, wp[23], b);
                    accA[dd][i] = a; accB[dd][i] = b;
                }
            }
        }
    }
    const float bias = b3[0];
#pragma unroll
    for (int dd = 0; dd < 2; ++dd) {
        const size_t obase = (size_t)((d0 + dd) * 128 + h0) * 128 + w;
#pragma unroll
        for (int i = 0; i < 2; ++i)
            out[obase + (size_t)i * 128] = fast_tanh(accA[dd][i] + accB[dd][i] + bias);
    }
}

extern "C" void kernel_launch(void* const* d_in, const int* in_sizes, int n_in,
                              void* d_out, int out_size, void* d_ws, size_t ws_size,
                              hipStream_t stream) {
    const float* cube = (const float*)d_in[0];
    const float* w1 = (const float*)d_in[1];
    const float* b1 = (const float*)d_in[2];
    const float* w2 = (const float*)d_in[3];
    const float* b2 = (const float*)d_in[4];
    const float* w3 = (const float*)d_in[5];
    const float* b3 = (const float*)d_in[6];
    float* out = (float*)d_out;

    // ws: w2frag@0 (7168B) | w3p@7168 (864B) | w1c@8032 (864B) | x0 @16384 | x1 | x2
    char* ws = (char*)d_ws;
    u16* w2frag = (u16*)ws;
    unsigned* w3p = (unsigned*)(ws + 7168);
    float* w1c = (float*)(ws + 8032);
    u16* x0 = (u16*)(ws + 16384);
    u16* x1 = (u16*)(ws + 16384 + (size_t)PVOX * sizeof(u16));
    u16* x2 = (u16*)(ws + 16384 + (size_t)PVOX * sizeof(u16) + (size_t)PVOX * 8 * sizeof(u16));

    for (int b = 0; b < 2; ++b) {
        if (b == 0) {
            integrate_kernel<<<dim3((PVOX + 255) / 256), dim3(256), 0, stream>>>(
                cube, x0, w1, w2, w3, w2frag, w3p, w1c, x1, x2);
        }
        // batch 1's x0 was produced by the fat conv3(b0) launch below
        conv1_kernel<<<dim3(VOX / 8 / 256), dim3(256), 0, stream>>>(x0, w1c, b1, x1);
        conv2_mfma_kernel<<<dim3(512), dim3(256), 0, stream>>>(x1, w2frag, b2, x2);
        if (b == 0) {
            // fat launch: 2048 conv3 blocks + 8192 integrate_light(b1) blocks
            conv3_kernel<<<dim3(2048 + VOX / 256), dim3(256), 0, stream>>>(
                x2, w3p, b3, out, cube + (size_t)VOX, x0);
        } else {
            conv3_kernel<<<dim3(2048), dim3(256), 0, stream>>>(
                x2, w3p, b3, out + (size_t)VOX, cube + (size_t)VOX, x0);
        }
    }
}